// Round 1
// baseline (556.892 us; speedup 1.0000x reference)
//
#include <hip/hip_runtime.h>
#include <math.h>

#define S_LEN 2048
#define E_DIM 1024
#define H_NUM 16
#define D_DIM 64

// ---------------------------------------------------------------------------
// Generic fp32 GEMM + bias: C[M,N] = A[M,K] @ B[K,N] + bias[N]
// 64x64 tile, BK=16, 256 threads, 4x4 accum per thread.
// ---------------------------------------------------------------------------
__global__ __launch_bounds__(256) void gemm_bias_kernel(
    const float* __restrict__ A, const float* __restrict__ B,
    const float* __restrict__ bias, float* __restrict__ C,
    int M, int N, int K)
{
    const int tid = threadIdx.x;
    const int tx = tid & 15;        // 0..15  -> n sub-col
    const int ty = tid >> 4;        // 0..15  -> m sub-row
    const int m0 = blockIdx.y * 64;
    const int n0 = blockIdx.x * 64;

    // As transposed: As[k][m], stride 68 (272B = 17*16 -> float4-aligned rows)
    __shared__ float As[16][68];
    __shared__ float Bs[16][64];

    float acc[4][4] = {};

    const int arow = tid >> 2;            // 0..63
    const int akc  = (tid & 3) << 2;      // 0,4,8,12
    const int bkr  = tid >> 4;            // 0..15
    const int bnc  = (tid & 15) << 2;     // 0..60

    for (int k0 = 0; k0 < K; k0 += 16) {
        const float4 av = *(const float4*)&A[(size_t)(m0 + arow) * K + k0 + akc];
        As[akc + 0][arow] = av.x;
        As[akc + 1][arow] = av.y;
        As[akc + 2][arow] = av.z;
        As[akc + 3][arow] = av.w;
        *(float4*)&Bs[bkr][bnc] = *(const float4*)&B[(size_t)(k0 + bkr) * N + n0 + bnc];
        __syncthreads();
#pragma unroll
        for (int kk = 0; kk < 16; ++kk) {
            const float4 a4 = *(const float4*)&As[kk][ty << 2];
            const float4 b4 = *(const float4*)&Bs[kk][tx << 2];
            acc[0][0] += a4.x * b4.x; acc[0][1] += a4.x * b4.y;
            acc[0][2] += a4.x * b4.z; acc[0][3] += a4.x * b4.w;
            acc[1][0] += a4.y * b4.x; acc[1][1] += a4.y * b4.y;
            acc[1][2] += a4.y * b4.z; acc[1][3] += a4.y * b4.w;
            acc[2][0] += a4.z * b4.x; acc[2][1] += a4.z * b4.y;
            acc[2][2] += a4.z * b4.z; acc[2][3] += a4.z * b4.w;
            acc[3][0] += a4.w * b4.x; acc[3][1] += a4.w * b4.y;
            acc[3][2] += a4.w * b4.z; acc[3][3] += a4.w * b4.w;
        }
        __syncthreads();
    }

    const float4 bv = *(const float4*)&bias[n0 + (tx << 2)];
#pragma unroll
    for (int i = 0; i < 4; ++i) {
        float4 ov;
        ov.x = acc[i][0] + bv.x;
        ov.y = acc[i][1] + bv.y;
        ov.z = acc[i][2] + bv.z;
        ov.w = acc[i][3] + bv.w;
        *(float4*)&C[(size_t)(m0 + (ty << 2) + i) * N + n0 + (tx << 2)] = ov;
    }
}

// ---------------------------------------------------------------------------
// fp32 flash attention over proj = [S, 3E] rows of (q | k | v).
// One block per (q-tile of 64 rows, head). 256 threads (16x16), 4x4 per thread.
// Online softmax; output written to attn_out [S, E].
// ---------------------------------------------------------------------------
__global__ __launch_bounds__(256) void flash_attn_kernel(
    const float* __restrict__ proj, float* __restrict__ attn_out)
{
    const int tid = threadIdx.x;
    const int tx = tid & 15;     // k-col / d-col group
    const int ty = tid >> 4;     // q-row group
    const int h  = blockIdx.y;
    const int q0 = blockIdx.x * 64;

    // Transposed tiles, stride 68 so &T[x][4*g] is 16B aligned.
    __shared__ float Qt[64][68];   // Qt[d][r]
    __shared__ float KPt[64][68];  // Kt[d][c] during scores; Pt[c][r] during PV
    __shared__ float Vs[64][64];   // Vs[c][d]

    const float* qbase = proj + (size_t)h * D_DIM;
    const float* kbase = proj + E_DIM + (size_t)h * D_DIM;
    const float* vbase = proj + 2 * E_DIM + (size_t)h * D_DIM;
    const int ld = 3 * E_DIM;

    const int lrow = tid >> 4;          // 0..15
    const int lcol = (tid & 15) << 2;   // 0..60 (d offset)

    // Load Q tile (transposed into Qt)
#pragma unroll
    for (int rep = 0; rep < 4; ++rep) {
        const int rr = rep * 16 + lrow;
        const float4 qv = *(const float4*)&qbase[(size_t)(q0 + rr) * ld + lcol];
        Qt[lcol + 0][rr] = qv.x;
        Qt[lcol + 1][rr] = qv.y;
        Qt[lcol + 2][rr] = qv.z;
        Qt[lcol + 3][rr] = qv.w;
    }

    float m[4], l[4], o[4][4];
#pragma unroll
    for (int i = 0; i < 4; ++i) {
        m[i] = -1e30f;
        l[i] = 0.f;
#pragma unroll
        for (int j = 0; j < 4; ++j) o[i][j] = 0.f;
    }

    const float scale = 0.125f;  // 1/sqrt(64)

    for (int t0 = 0; t0 < S_LEN; t0 += 64) {
        // Load K (transposed) and V tiles
#pragma unroll
        for (int rep = 0; rep < 4; ++rep) {
            const int rr = rep * 16 + lrow;
            const float4 kv = *(const float4*)&kbase[(size_t)(t0 + rr) * ld + lcol];
            KPt[lcol + 0][rr] = kv.x;
            KPt[lcol + 1][rr] = kv.y;
            KPt[lcol + 2][rr] = kv.z;
            KPt[lcol + 3][rr] = kv.w;
            *(float4*)&Vs[rr][lcol] = *(const float4*)&vbase[(size_t)(t0 + rr) * ld + lcol];
        }
        __syncthreads();

        // S = Q @ K^T (4x4 per thread), rows ty*4+i, cols tx*4+j
        float s[4][4] = {};
#pragma unroll 8
        for (int d = 0; d < 64; ++d) {
            const float4 q4 = *(const float4*)&Qt[d][ty << 2];
            const float4 k4 = *(const float4*)&KPt[d][tx << 2];
            s[0][0] += q4.x * k4.x; s[0][1] += q4.x * k4.y;
            s[0][2] += q4.x * k4.z; s[0][3] += q4.x * k4.w;
            s[1][0] += q4.y * k4.x; s[1][1] += q4.y * k4.y;
            s[1][2] += q4.y * k4.z; s[1][3] += q4.y * k4.w;
            s[2][0] += q4.z * k4.x; s[2][1] += q4.z * k4.y;
            s[2][2] += q4.z * k4.z; s[2][3] += q4.z * k4.w;
            s[3][0] += q4.w * k4.x; s[3][1] += q4.w * k4.y;
            s[3][2] += q4.w * k4.z; s[3][3] += q4.w * k4.w;
        }
        __syncthreads();   // all Kt reads done before Pt overwrites the buffer

        // Online softmax update (per row i). Row group = 16 consecutive lanes.
#pragma unroll
        for (int i = 0; i < 4; ++i) {
            float tmax = s[i][0] * scale;
            tmax = fmaxf(tmax, s[i][1] * scale);
            tmax = fmaxf(tmax, s[i][2] * scale);
            tmax = fmaxf(tmax, s[i][3] * scale);
            tmax = fmaxf(tmax, __shfl_xor(tmax, 1, 16));
            tmax = fmaxf(tmax, __shfl_xor(tmax, 2, 16));
            tmax = fmaxf(tmax, __shfl_xor(tmax, 4, 16));
            tmax = fmaxf(tmax, __shfl_xor(tmax, 8, 16));
            const float mnew = fmaxf(m[i], tmax);
            const float f = __expf(m[i] - mnew);
            l[i] *= f;
#pragma unroll
            for (int j = 0; j < 4; ++j) o[i][j] *= f;
            float psum = 0.f;
#pragma unroll
            for (int j = 0; j < 4; ++j) {
                const float p = __expf(s[i][j] * scale - mnew);
                s[i][j] = p;
                psum += p;
            }
            psum += __shfl_xor(psum, 1, 16);
            psum += __shfl_xor(psum, 2, 16);
            psum += __shfl_xor(psum, 4, 16);
            psum += __shfl_xor(psum, 8, 16);
            l[i] += psum;
            m[i] = mnew;
        }

        // Write P transposed: Pt[c][r]
#pragma unroll
        for (int i = 0; i < 4; ++i)
#pragma unroll
            for (int j = 0; j < 4; ++j)
                KPt[(tx << 2) + j][(ty << 2) + i] = s[i][j];
        __syncthreads();

        // O += P @ V  (rows ty*4+i, d-cols tx*4+j)
#pragma unroll 8
        for (int c = 0; c < 64; ++c) {
            const float4 p4 = *(const float4*)&KPt[c][ty << 2];
            const float4 v4 = *(const float4*)&Vs[c][tx << 2];
            o[0][0] += p4.x * v4.x; o[0][1] += p4.x * v4.y;
            o[0][2] += p4.x * v4.z; o[0][3] += p4.x * v4.w;
            o[1][0] += p4.y * v4.x; o[1][1] += p4.y * v4.y;
            o[1][2] += p4.y * v4.z; o[1][3] += p4.y * v4.w;
            o[2][0] += p4.z * v4.x; o[2][1] += p4.z * v4.y;
            o[2][2] += p4.z * v4.z; o[2][3] += p4.z * v4.w;
            o[3][0] += p4.w * v4.x; o[3][1] += p4.w * v4.y;
            o[3][2] += p4.w * v4.z; o[3][3] += p4.w * v4.w;
        }
        __syncthreads();   // Pt/Vs reads done before next tile's loads
    }

    // Normalize and write out: attn_out[q0+r][h*64 + d]
#pragma unroll
    for (int i = 0; i < 4; ++i) {
        const float inv = 1.f / l[i];
        float4 ov;
        ov.x = o[i][0] * inv;
        ov.y = o[i][1] * inv;
        ov.z = o[i][2] * inv;
        ov.w = o[i][3] * inv;
        const int row = q0 + (ty << 2) + i;
        *(float4*)&attn_out[(size_t)row * E_DIM + h * D_DIM + (tx << 2)] = ov;
    }
}

// ---------------------------------------------------------------------------
extern "C" void kernel_launch(void* const* d_in, const int* in_sizes, int n_in,
                              void* d_out, int out_size, void* d_ws, size_t ws_size,
                              hipStream_t stream)
{
    (void)in_sizes; (void)n_in; (void)out_size; (void)ws_size;

    const float* qkv   = (const float*)d_in[0];
    const float* w_in  = (const float*)d_in[1];
    const float* b_in  = (const float*)d_in[2];
    const float* w_out = (const float*)d_in[3];
    const float* b_out = (const float*)d_in[4];
    float* out = (float*)d_out;

    float* proj = (float*)d_ws;                           // [S, 3E] = 25.2 MB
    float* attn = proj + (size_t)S_LEN * 3 * E_DIM;       // [S, E]  =  8.4 MB

    // 1) proj = qkv @ w_in + b_in          [2048,1024]@[1024,3072]
    gemm_bias_kernel<<<dim3(3 * E_DIM / 64, S_LEN / 64), 256, 0, stream>>>(
        qkv, w_in, b_in, proj, S_LEN, 3 * E_DIM, E_DIM);

    // 2) flash attention per (q-tile, head)
    flash_attn_kernel<<<dim3(S_LEN / 64, H_NUM), 256, 0, stream>>>(proj, attn);

    // 3) out = attn @ w_out + b_out        [2048,1024]@[1024,1024]
    gemm_bias_kernel<<<dim3(E_DIM / 64, S_LEN / 64), 256, 0, stream>>>(
        attn, w_out, b_out, out, S_LEN, E_DIM, E_DIM);
}

// Round 2
// 199.509 us; speedup vs baseline: 2.7913x; 2.7913x over previous
//
#include <hip/hip_runtime.h>
#include <math.h>

typedef short bf16x8 __attribute__((ext_vector_type(8)));
typedef float f32x4 __attribute__((ext_vector_type(4)));
typedef unsigned short u16x4 __attribute__((ext_vector_type(4)));

#define S_LEN 2048
#define E_DIM 1024
#define H_NUM 16
#define D_DIM 64
#define LDP   (3 * E_DIM)

#define MFMA16(a, b, c) __builtin_amdgcn_mfma_f32_16x16x32_bf16((a), (b), (c), 0, 0, 0)

__device__ __forceinline__ unsigned short f2bf(float f) {
    union { float f; unsigned int u; } v; v.f = f;
    unsigned int r = v.u + 0x7FFFu + ((v.u >> 16) & 1u);
    return (unsigned short)(r >> 16);
}
__device__ __forceinline__ float bf2f(unsigned short h) {
    union { unsigned int u; float f; } v; v.u = ((unsigned int)h) << 16;
    return v.f;
}

// ---------------------------------------------------------------------------
// Split+transpose weights: B[K][N] fp32 -> Bth[N][K], Btl[N][K] bf16 (hi/lo)
// ---------------------------------------------------------------------------
__global__ __launch_bounds__(256) void split_transpose_kernel(
    const float* __restrict__ B, unsigned short* __restrict__ Bth,
    unsigned short* __restrict__ Btl, int K, int N)
{
    __shared__ float tile[64][65];
    const int k0 = blockIdx.y * 64;
    const int n0 = blockIdx.x * 64;
    const int t  = threadIdx.x;
    const int r4 = t >> 6;      // 0..3
    const int c  = t & 63;
#pragma unroll
    for (int rep = 0; rep < 16; ++rep) {
        const int row = rep * 4 + r4;
        tile[row][c] = B[(size_t)(k0 + row) * N + n0 + c];
    }
    __syncthreads();
#pragma unroll
    for (int rep = 0; rep < 16; ++rep) {
        const int n = rep * 4 + r4;
        const float v = tile[c][n];           // c = k index (bank-conflict-free: stride 65)
        const unsigned short hi = f2bf(v);
        const unsigned short lo = f2bf(v - bf2f(hi));
        Bth[(size_t)(n0 + n) * K + k0 + c] = hi;
        Btl[(size_t)(n0 + n) * K + k0 + c] = lo;
    }
}

// ---------------------------------------------------------------------------
// Split-bf16 MFMA GEMM: C[M,N] = A[M,K](fp32) @ B[K,N] + bias, B pre-split
// as Bt hi/lo [N][K] bf16. 128x128 tile, BK=32, 256 thr (4 waves, 2x2).
// 3-pass: ah*bh + ah*bl + al*bh  (al*bl dropped, ~1e-5 residual).
// ---------------------------------------------------------------------------
template <int OUT_BF16>
__global__ __launch_bounds__(256) void gemm_split_kernel(
    const float* __restrict__ A, const unsigned short* __restrict__ Bth,
    const unsigned short* __restrict__ Btl, const float* __restrict__ bias,
    void* __restrict__ Cout, int M, int N, int K, int nbx)
{
    // XCD-aware swizzle (grid % 8 == 0 for both launches)
    const int nwg = gridDim.x;
    const int bid = blockIdx.x;
    const int qch = nwg >> 3;
    const int swz = (bid & 7) * qch + (bid >> 3);
    const int n0 = (swz % nbx) * 128;
    const int m0 = (swz / nbx) * 128;

    // LDS: stride 40 elems (80B) rows -> conflict-light b128 frag reads
    __shared__ unsigned short lds[4 * 128 * 40];
    const int AH = 0, AL = 5120, BH = 10240, BL = 15360;

    const int t    = threadIdx.x;
    const int wid  = t >> 6, lane = t & 63;
    const int wr   = wid >> 1, wc = wid & 1;
    const int lc   = lane & 15, g = lane >> 4;

    const int srow = t >> 1;          // 0..127
    const int skc  = (t & 1) * 16;    // 0 or 16

    f32x4 acc[4][4];
    const f32x4 zf = {0.f, 0.f, 0.f, 0.f};
#pragma unroll
    for (int mi = 0; mi < 4; ++mi)
#pragma unroll
        for (int ni = 0; ni < 4; ++ni) acc[mi][ni] = zf;

    for (int k0 = 0; k0 < K; k0 += 32) {
        // --- stage A (fp32 -> hi/lo bf16) ---
        const float* ga = &A[(size_t)(m0 + srow) * K + k0 + skc];
        float av[16];
        {
            const float4 a0 = ((const float4*)ga)[0];
            const float4 a1 = ((const float4*)ga)[1];
            const float4 a2 = ((const float4*)ga)[2];
            const float4 a3 = ((const float4*)ga)[3];
            av[0]=a0.x; av[1]=a0.y; av[2]=a0.z; av[3]=a0.w;
            av[4]=a1.x; av[5]=a1.y; av[6]=a1.z; av[7]=a1.w;
            av[8]=a2.x; av[9]=a2.y; av[10]=a2.z; av[11]=a2.w;
            av[12]=a3.x; av[13]=a3.y; av[14]=a3.z; av[15]=a3.w;
        }
        bf16x8 h0, h1, l0, l1;
#pragma unroll
        for (int i = 0; i < 8; ++i) {
            unsigned short hh = f2bf(av[i]);
            h0[i] = (short)hh;
            l0[i] = (short)f2bf(av[i] - bf2f(hh));
        }
#pragma unroll
        for (int i = 0; i < 8; ++i) {
            unsigned short hh = f2bf(av[8 + i]);
            h1[i] = (short)hh;
            l1[i] = (short)f2bf(av[8 + i] - bf2f(hh));
        }
        *(bf16x8*)&lds[AH + srow * 40 + skc]     = h0;
        *(bf16x8*)&lds[AH + srow * 40 + skc + 8] = h1;
        *(bf16x8*)&lds[AL + srow * 40 + skc]     = l0;
        *(bf16x8*)&lds[AL + srow * 40 + skc + 8] = l1;

        // --- stage B (pre-split bf16, straight copy) ---
        {
            const uint4 bh0 = *(const uint4*)&Bth[(size_t)(n0 + srow) * K + k0 + skc];
            const uint4 bh1 = *(const uint4*)&Bth[(size_t)(n0 + srow) * K + k0 + skc + 8];
            const uint4 bl0 = *(const uint4*)&Btl[(size_t)(n0 + srow) * K + k0 + skc];
            const uint4 bl1 = *(const uint4*)&Btl[(size_t)(n0 + srow) * K + k0 + skc + 8];
            *(uint4*)&lds[BH + srow * 40 + skc]     = bh0;
            *(uint4*)&lds[BH + srow * 40 + skc + 8] = bh1;
            *(uint4*)&lds[BL + srow * 40 + skc]     = bl0;
            *(uint4*)&lds[BL + srow * 40 + skc + 8] = bl1;
        }
        __syncthreads();

        // --- compute ---
        bf16x8 bh[4], bl[4];
#pragma unroll
        for (int ni = 0; ni < 4; ++ni) {
            const int br = wc * 64 + ni * 16 + lc;
            bh[ni] = *(const bf16x8*)&lds[BH + br * 40 + g * 8];
            bl[ni] = *(const bf16x8*)&lds[BL + br * 40 + g * 8];
        }
#pragma unroll
        for (int mi = 0; mi < 4; ++mi) {
            const int ar = wr * 64 + mi * 16 + lc;
            const bf16x8 ah = *(const bf16x8*)&lds[AH + ar * 40 + g * 8];
            const bf16x8 al = *(const bf16x8*)&lds[AL + ar * 40 + g * 8];
#pragma unroll
            for (int ni = 0; ni < 4; ++ni) {
                acc[mi][ni] = MFMA16(ah, bh[ni], acc[mi][ni]);
                acc[mi][ni] = MFMA16(ah, bl[ni], acc[mi][ni]);
                acc[mi][ni] = MFMA16(al, bh[ni], acc[mi][ni]);
            }
        }
        __syncthreads();
    }

    // --- epilogue: bias + store ---
#pragma unroll
    for (int ni = 0; ni < 4; ++ni) {
        const int col = n0 + wc * 64 + ni * 16 + lc;
        const float bv = bias[col];
#pragma unroll
        for (int mi = 0; mi < 4; ++mi) {
            const int rbase = m0 + wr * 64 + mi * 16 + g * 4;
#pragma unroll
            for (int i = 0; i < 4; ++i) {
                const float v = acc[mi][ni][i] + bv;
                if (OUT_BF16)
                    ((unsigned short*)Cout)[(size_t)(rbase + i) * N + col] = f2bf(v);
                else
                    ((float*)Cout)[(size_t)(rbase + i) * N + col] = v;
            }
        }
    }
}

// ---------------------------------------------------------------------------
// MFMA flash attention. proj bf16 [S][3E] (q|k|v). Block = 64 Q rows x head,
// 4 waves; each wave owns 16 Q rows. 16x16x32 bf16 MFMA. Online softmax.
// K/Vt double-buffered in LDS, XOR-swizzled rows; V transposed at staging.
// ---------------------------------------------------------------------------
__global__ __launch_bounds__(256) void attn_mfma_kernel(
    const unsigned short* __restrict__ proj, float* __restrict__ attn)
{
    __shared__ unsigned short lds[24576];  // Q 4096 | K 2x4096 | Vt 2x4096 | P 4096
    const int Q_OFF = 0, K_OFF = 4096, V_OFF = 12288, P_OFF = 20480;

    const int t    = threadIdx.x;
    const int wid  = t >> 6, lane = t & 63;
    const int lc   = lane & 15, g = lane >> 4;

    // XCD swizzle: 512 blocks -> same-head blocks contiguous per XCD
    const int bid = blockIdx.x;
    const int swb = (bid & 7) * 64 + (bid >> 3);
    const int qt  = swb & 31;
    const int h   = swb >> 5;
    const int q0  = qt * 64;

    const size_t qoff = (size_t)h * D_DIM;
    const size_t koff = E_DIM + (size_t)h * D_DIM;
    const size_t voff = 2 * E_DIM + (size_t)h * D_DIM;

    // --- stage Q (row-major, XOR swizzle) ---
    {
        const int r = t >> 2;
        const int s = (t & 3) * 16;
        const unsigned short* gq = &proj[(size_t)(q0 + r) * LDP + qoff + s];
        const uint4 v0 = ((const uint4*)gq)[0];
        const uint4 v1 = ((const uint4*)gq)[1];
        const int sw = (r & 7) << 3;
        *(uint4*)&lds[Q_OFF + r * 64 + (s ^ sw)]       = v0;
        *(uint4*)&lds[Q_OFF + r * 64 + ((s + 8) ^ sw)] = v1;
    }

    uint4 ka, kb;
    u16x4 vr[4];
    {   // prefetch tile 0
        const int r = t >> 2, s = (t & 3) * 16;
        const unsigned short* gk = &proj[(size_t)r * LDP + koff + s];
        ka = ((const uint4*)gk)[0];
        kb = ((const uint4*)gk)[1];
        const int kv = (t & 15) * 4, d0 = (t >> 4) * 4;
#pragma unroll
        for (int r2 = 0; r2 < 4; ++r2)
            vr[r2] = *(const u16x4*)&proj[(size_t)(kv + r2) * LDP + voff + d0];
    }
    {   // write tile 0 -> buf 0
        const int r = t >> 2, s = (t & 3) * 16;
        const int sw = (r & 7) << 3;
        *(uint4*)&lds[K_OFF + r * 64 + (s ^ sw)]       = ka;
        *(uint4*)&lds[K_OFF + r * 64 + ((s + 8) ^ sw)] = kb;
        const int kv = (t & 15) * 4, d0 = (t >> 4) * 4;
#pragma unroll
        for (int j = 0; j < 4; ++j) {
            u16x4 w; w[0] = vr[0][j]; w[1] = vr[1][j]; w[2] = vr[2][j]; w[3] = vr[3][j];
            const int d = d0 + j, swv = (d & 7) << 3;
            *(u16x4*)&lds[V_OFF + d * 64 + (kv ^ swv)] = w;
        }
    }
    __syncthreads();

    // hoist Q fragments (wave's 16 rows)
    bf16x8 qA0, qA1;
    {
        const int r = wid * 16 + lc;
        const int sw = (r & 7) << 3;
        qA0 = *(const bf16x8*)&lds[Q_OFF + r * 64 + ((g * 8) ^ sw)];
        qA1 = *(const bf16x8*)&lds[Q_OFF + r * 64 + ((32 + g * 8) ^ sw)];
    }

    f32x4 oacc[4];
    float mrun[4], lrun[4];
    const f32x4 zf = {0.f, 0.f, 0.f, 0.f};
#pragma unroll
    for (int i = 0; i < 4; ++i) { oacc[i] = zf; mrun[i] = -1e30f; lrun[i] = 0.f; }

    const float SCALE = 0.125f;
    int buf = 0;

    for (int tt = 0; tt < S_LEN / 64; ++tt) {
        if (tt + 1 < S_LEN / 64) {   // prefetch next tile into regs
            const int t0n = (tt + 1) * 64;
            const int r = t >> 2, s = (t & 3) * 16;
            const unsigned short* gk = &proj[(size_t)(t0n + r) * LDP + koff + s];
            ka = ((const uint4*)gk)[0];
            kb = ((const uint4*)gk)[1];
            const int kv = (t & 15) * 4, d0 = (t >> 4) * 4;
#pragma unroll
            for (int r2 = 0; r2 < 4; ++r2)
                vr[r2] = *(const u16x4*)&proj[(size_t)(t0n + kv + r2) * LDP + voff + d0];
        }

        // --- QK^T ---
        f32x4 sacc[4];
#pragma unroll
        for (int c = 0; c < 4; ++c) sacc[c] = zf;
#pragma unroll
        for (int c = 0; c < 4; ++c) {
            const int kr = c * 16 + lc;
            const int sw = (kr & 7) << 3;
            const bf16x8 kf0 = *(const bf16x8*)&lds[K_OFF + buf * 4096 + kr * 64 + ((g * 8) ^ sw)];
            const bf16x8 kf1 = *(const bf16x8*)&lds[K_OFF + buf * 4096 + kr * 64 + ((32 + g * 8) ^ sw)];
            sacc[c] = MFMA16(qA0, kf0, sacc[c]);
            sacc[c] = MFMA16(qA1, kf1, sacc[c]);
        }

        // --- online softmax (row = 4g + i within wave tile) ---
#pragma unroll
        for (int i = 0; i < 4; ++i) {
            const float s0 = sacc[0][i] * SCALE, s1 = sacc[1][i] * SCALE;
            const float s2 = sacc[2][i] * SCALE, s3 = sacc[3][i] * SCALE;
            float rmax = fmaxf(fmaxf(s0, s1), fmaxf(s2, s3));
            rmax = fmaxf(rmax, __shfl_xor(rmax, 1, 16));
            rmax = fmaxf(rmax, __shfl_xor(rmax, 2, 16));
            rmax = fmaxf(rmax, __shfl_xor(rmax, 4, 16));
            rmax = fmaxf(rmax, __shfl_xor(rmax, 8, 16));
            const float mnew = fmaxf(mrun[i], rmax);
            const float fs = __expf(mrun[i] - mnew);
            const float p0 = __expf(s0 - mnew), p1 = __expf(s1 - mnew);
            const float p2 = __expf(s2 - mnew), p3 = __expf(s3 - mnew);
            float ps = (p0 + p1) + (p2 + p3);
            ps += __shfl_xor(ps, 1, 16);
            ps += __shfl_xor(ps, 2, 16);
            ps += __shfl_xor(ps, 4, 16);
            ps += __shfl_xor(ps, 8, 16);
            lrun[i] = lrun[i] * fs + ps;
            mrun[i] = mnew;
            oacc[0][i] *= fs; oacc[1][i] *= fs; oacc[2][i] *= fs; oacc[3][i] *= fs;
            const int prow = wid * 16 + 4 * g + i;
            const int psw = ((4 * g + i) & 7) << 3;
            lds[P_OFF + prow * 64 + ((lc)      ^ psw)] = f2bf(p0);
            lds[P_OFF + prow * 64 + ((16 + lc) ^ psw)] = f2bf(p1);
            lds[P_OFF + prow * 64 + ((32 + lc) ^ psw)] = f2bf(p2);
            lds[P_OFF + prow * 64 + ((48 + lc) ^ psw)] = f2bf(p3);
        }

        // --- P fragments (wave-private region, no barrier needed) ---
        bf16x8 pA0, pA1;
        {
            const int pr = wid * 16 + lc;
            const int sw = (lc & 7) << 3;
            pA0 = *(const bf16x8*)&lds[P_OFF + pr * 64 + ((g * 8) ^ sw)];
            pA1 = *(const bf16x8*)&lds[P_OFF + pr * 64 + ((32 + g * 8) ^ sw)];
        }

        // --- PV ---
#pragma unroll
        for (int dt = 0; dt < 4; ++dt) {
            const int vrow = dt * 16 + lc;
            const int sw = (vrow & 7) << 3;
            const bf16x8 vB0 = *(const bf16x8*)&lds[V_OFF + buf * 4096 + vrow * 64 + ((g * 8) ^ sw)];
            const bf16x8 vB1 = *(const bf16x8*)&lds[V_OFF + buf * 4096 + vrow * 64 + ((32 + g * 8) ^ sw)];
            oacc[dt] = MFMA16(pA0, vB0, oacc[dt]);
            oacc[dt] = MFMA16(pA1, vB1, oacc[dt]);
        }

        // --- write next tile to other buffer ---
        if (tt + 1 < S_LEN / 64) {
            const int r = t >> 2, s = (t & 3) * 16;
            const int sw = (r & 7) << 3;
            const int ob = (buf ^ 1) * 4096;
            *(uint4*)&lds[K_OFF + ob + r * 64 + (s ^ sw)]       = ka;
            *(uint4*)&lds[K_OFF + ob + r * 64 + ((s + 8) ^ sw)] = kb;
            const int kv = (t & 15) * 4, d0 = (t >> 4) * 4;
#pragma unroll
            for (int j = 0; j < 4; ++j) {
                u16x4 w; w[0] = vr[0][j]; w[1] = vr[1][j]; w[2] = vr[2][j]; w[3] = vr[3][j];
                const int d = d0 + j, swv = (d & 7) << 3;
                *(u16x4*)&lds[V_OFF + ob + d * 64 + (kv ^ swv)] = w;
            }
            __syncthreads();
        }
        buf ^= 1;
    }

    // --- epilogue ---
#pragma unroll
    for (int i = 0; i < 4; ++i) {
        const float inv = 1.f / lrun[i];
        const int row = q0 + wid * 16 + 4 * g + i;
#pragma unroll
        for (int dt = 0; dt < 4; ++dt) {
            const int col = h * 64 + dt * 16 + lc;
            attn[(size_t)row * E_DIM + col] = oacc[dt][i] * inv;
        }
    }
}

// ---------------------------------------------------------------------------
extern "C" void kernel_launch(void* const* d_in, const int* in_sizes, int n_in,
                              void* d_out, int out_size, void* d_ws, size_t ws_size,
                              hipStream_t stream)
{
    (void)in_sizes; (void)n_in; (void)out_size; (void)ws_size;

    const float* qkv   = (const float*)d_in[0];
    const float* w_in  = (const float*)d_in[1];
    const float* b_in  = (const float*)d_in[2];
    const float* w_out = (const float*)d_in[3];
    const float* b_out = (const float*)d_in[4];
    float* out = (float*)d_out;

    unsigned char* ws = (unsigned char*)d_ws;
    unsigned short* Bth1 = (unsigned short*)(ws);              // 6.29 MB
    unsigned short* Btl1 = (unsigned short*)(ws + 6291456);    // 6.29 MB
    unsigned short* Bth2 = (unsigned short*)(ws + 12582912);   // 2.10 MB
    unsigned short* Btl2 = (unsigned short*)(ws + 14680064);   // 2.10 MB
    unsigned short* proj = (unsigned short*)(ws + 16777216);   // 12.58 MB bf16
    float* attn = (float*)(ws);  // 8.39 MB, reuses Bth1/Btl1 after GEMM1

    // 1) weight split+transpose
    split_transpose_kernel<<<dim3(48, 16), 256, 0, stream>>>(w_in, Bth1, Btl1, E_DIM, 3 * E_DIM);
    split_transpose_kernel<<<dim3(16, 16), 256, 0, stream>>>(w_out, Bth2, Btl2, E_DIM, E_DIM);

    // 2) proj = qkv @ w_in + b_in  (bf16 out)   [2048,1024]@[1024,3072]
    gemm_split_kernel<1><<<384, 256, 0, stream>>>(
        qkv, Bth1, Btl1, b_in, (void*)proj, S_LEN, 3 * E_DIM, E_DIM, 24);

    // 3) flash attention (bf16 MFMA)
    attn_mfma_kernel<<<512, 256, 0, stream>>>(proj, attn);

    // 4) out = attn @ w_out + b_out (fp32 out)  [2048,1024]@[1024,1024]
    gemm_split_kernel<0><<<128, 256, 0, stream>>>(
        attn, Bth2, Btl2, b_out, (void*)out, S_LEN, E_DIM, E_DIM, 8);
}

// Round 3
// 146.292 us; speedup vs baseline: 3.8067x; 1.3638x over previous
//
#include <hip/hip_runtime.h>
#include <math.h>

typedef short bf16x8 __attribute__((ext_vector_type(8)));
typedef _Float16 f16x8 __attribute__((ext_vector_type(8)));
typedef _Float16 f16x4 __attribute__((ext_vector_type(4)));
typedef float f32x4 __attribute__((ext_vector_type(4)));
typedef unsigned short u16x4 __attribute__((ext_vector_type(4)));

#define S_LEN 2048
#define E_DIM 1024
#define H_NUM 16
#define D_DIM 64
#define LDP   (3 * E_DIM)
#define NT    (S_LEN / 64)
// softmax scale folded into Q at GEMM1 epilogue: 1/sqrt(64) * log2(e)
#define QSCALE 0.18033688011112042f

#define MFMA16(a, b, c)  __builtin_amdgcn_mfma_f32_16x16x32_bf16((a), (b), (c), 0, 0, 0)
#define MFMA16H(a, b, c) __builtin_amdgcn_mfma_f32_16x16x32_f16((a), (b), (c), 0, 0, 0)

__device__ __forceinline__ unsigned short f2bf(float f) {
    union { float f; unsigned int u; } v; v.f = f;
    unsigned int r = v.u + 0x7FFFu + ((v.u >> 16) & 1u);
    return (unsigned short)(r >> 16);
}
__device__ __forceinline__ float exp2_fast(float x) {
    float r; asm("v_exp_f32 %0, %1" : "=v"(r) : "v"(x)); return r;
}
__device__ __forceinline__ unsigned int cvt_pk_bf16(float lo, float hi) {
    unsigned int r;
    asm("v_cvt_pk_bf16_f32 %0, %1, %2" : "=v"(r) : "v"(lo), "v"(hi));
    return r;
}

// ---------------------------------------------------------------------------
// Split fp32 activations -> f16 hi/lo pair (A exact to ~22 mantissa bits)
// ---------------------------------------------------------------------------
__global__ __launch_bounds__(256) void split_a_kernel(
    const float* __restrict__ A, _Float16* __restrict__ Ah,
    _Float16* __restrict__ Al, int n4)
{
    const int i = blockIdx.x * 256 + threadIdx.x;
    if (i >= n4) return;
    const float4 v = ((const float4*)A)[i];
    f16x4 h, l;
    h[0] = (_Float16)v.x; l[0] = (_Float16)(v.x - (float)h[0]);
    h[1] = (_Float16)v.y; l[1] = (_Float16)(v.y - (float)h[1]);
    h[2] = (_Float16)v.z; l[2] = (_Float16)(v.z - (float)h[2]);
    h[3] = (_Float16)v.w; l[3] = (_Float16)(v.w - (float)h[3]);
    ((f16x4*)Ah)[i] = h;
    ((f16x4*)Al)[i] = l;
}

// ---------------------------------------------------------------------------
// Transpose + convert weights: B[K][N] fp32 -> Bt[N][K] f16
// ---------------------------------------------------------------------------
__global__ __launch_bounds__(256) void transpose_convert_kernel(
    const float* __restrict__ B, _Float16* __restrict__ Bt, int K, int N)
{
    __shared__ float tile[64][65];
    const int k0 = blockIdx.y * 64;
    const int n0 = blockIdx.x * 64;
    const int t = threadIdx.x, r4 = t >> 6, c = t & 63;
#pragma unroll
    for (int rep = 0; rep < 16; ++rep)
        tile[rep * 4 + r4][c] = B[(size_t)(k0 + rep * 4 + r4) * N + n0 + c];
    __syncthreads();
#pragma unroll
    for (int rep = 0; rep < 16; ++rep) {
        const int n = rep * 4 + r4;
        Bt[(size_t)(n0 + n) * K + k0 + c] = (_Float16)tile[c][n];
    }
}

// ---------------------------------------------------------------------------
// 2-pass f16 MFMA GEMM: C = (Ah+Al)[M,K] @ Bt^T + bias. Bt is [N][K] f16.
// 128x128 tile, BK=32, 256 thr (4 waves, 2x2). acc = mfma(ah,b) + mfma(al,b).
// OUT_MODE 1: bf16 out, scale cols < E_DIM by QSCALE (proj for attention).
// OUT_MODE 0: fp32 out (final output).
// ---------------------------------------------------------------------------
template <int OUT_MODE>
__global__ __launch_bounds__(256) void gemm_f16_kernel(
    const _Float16* __restrict__ Ah, const _Float16* __restrict__ Al,
    const _Float16* __restrict__ Bt, const float* __restrict__ bias,
    void* __restrict__ Cout, int M, int N, int K, int nbx)
{
    const int nwg = gridDim.x;
    const int bid = blockIdx.x;
    const int qch = nwg >> 3;
    const int swz = (bid & 7) * qch + (bid >> 3);
    const int n0 = (swz % nbx) * 128;
    const int m0 = (swz / nbx) * 128;

    __shared__ unsigned short lds[3 * 128 * 40];  // stride-40 rows: conflict-light
    const int AH = 0, AL = 5120, BH = 10240;

    const int t = threadIdx.x;
    const int wid = t >> 6, lane = t & 63;
    const int wr = wid >> 1, wc = wid & 1;
    const int lc = lane & 15, g = lane >> 4;

    const int srow = t >> 1;        // 0..127
    const int skc  = (t & 1) * 16;  // 0 or 16

    f32x4 acc[4][4];
    const f32x4 zf = {0.f, 0.f, 0.f, 0.f};
#pragma unroll
    for (int mi = 0; mi < 4; ++mi)
#pragma unroll
        for (int ni = 0; ni < 4; ++ni) acc[mi][ni] = zf;

    for (int k0 = 0; k0 < K; k0 += 32) {
        const size_t abase = (size_t)(m0 + srow) * K + k0 + skc;
        const size_t bbase = (size_t)(n0 + srow) * K + k0 + skc;
        const uint4 ah0 = *(const uint4*)&Ah[abase];
        const uint4 ah1 = *(const uint4*)&Ah[abase + 8];
        const uint4 al0 = *(const uint4*)&Al[abase];
        const uint4 al1 = *(const uint4*)&Al[abase + 8];
        const uint4 bh0 = *(const uint4*)&Bt[bbase];
        const uint4 bh1 = *(const uint4*)&Bt[bbase + 8];
        *(uint4*)&lds[AH + srow * 40 + skc]     = ah0;
        *(uint4*)&lds[AH + srow * 40 + skc + 8] = ah1;
        *(uint4*)&lds[AL + srow * 40 + skc]     = al0;
        *(uint4*)&lds[AL + srow * 40 + skc + 8] = al1;
        *(uint4*)&lds[BH + srow * 40 + skc]     = bh0;
        *(uint4*)&lds[BH + srow * 40 + skc + 8] = bh1;
        __syncthreads();

        f16x8 bfr[4];
#pragma unroll
        for (int ni = 0; ni < 4; ++ni) {
            const int br = wc * 64 + ni * 16 + lc;
            bfr[ni] = *(const f16x8*)&lds[BH + br * 40 + g * 8];
        }
#pragma unroll
        for (int mi = 0; mi < 4; ++mi) {
            const int ar = wr * 64 + mi * 16 + lc;
            const f16x8 ah = *(const f16x8*)&lds[AH + ar * 40 + g * 8];
            const f16x8 al = *(const f16x8*)&lds[AL + ar * 40 + g * 8];
#pragma unroll
            for (int ni = 0; ni < 4; ++ni)
                acc[mi][ni] = MFMA16H(ah, bfr[ni], acc[mi][ni]);
#pragma unroll
            for (int ni = 0; ni < 4; ++ni)
                acc[mi][ni] = MFMA16H(al, bfr[ni], acc[mi][ni]);
        }
        __syncthreads();
    }

#pragma unroll
    for (int ni = 0; ni < 4; ++ni) {
        const int col = n0 + wc * 64 + ni * 16 + lc;
        const float bv = bias[col];
        float sc = 1.f;
        if (OUT_MODE == 1) sc = (col < E_DIM) ? QSCALE : 1.f;
#pragma unroll
        for (int mi = 0; mi < 4; ++mi) {
            const int rbase = m0 + wr * 64 + mi * 16 + g * 4;
#pragma unroll
            for (int i = 0; i < 4; ++i) {
                const float v = acc[mi][ni][i] + bv;
                if (OUT_MODE == 1)
                    ((unsigned short*)Cout)[(size_t)(rbase + i) * N + col] = f2bf(v * sc);
                else
                    ((float*)Cout)[(size_t)(rbase + i) * N + col] = v;
            }
        }
    }
}

// ---------------------------------------------------------------------------
// MFMA flash attention, swapped-QK^T softmax. proj bf16 [S][3E], Q pre-scaled
// by QSCALE. Block = 64 Q rows x head, 4 waves (16 q-rows each). Single
// K/V LDS buffer + register prefetch (T14). Output f16 hi/lo for GEMM2.
// sacc = mfma(Kfrag, Qfrag): lane lc owns q-row (wid*16+lc); 16 S-vals in reg.
// ---------------------------------------------------------------------------
__global__ __launch_bounds__(256) void attn_mfma_kernel(
    const unsigned short* __restrict__ proj,
    _Float16* __restrict__ Oh, _Float16* __restrict__ Ol)
{
    __shared__ unsigned short lds[16384];  // Q 8KB | K 8KB | Vt 8KB | P 8KB
    const int Q_OFF = 0, K_OFF = 4096, V_OFF = 8192, P_OFF = 12288;

    const int t = threadIdx.x;
    const int wid = t >> 6, lane = t & 63;
    const int lc = lane & 15, g = lane >> 4;

    // XCD swizzle: same-head blocks contiguous per XCD (K/V L2 locality)
    const int bid = blockIdx.x;
    const int swb = (bid & 7) * 64 + (bid >> 3);
    const int qt = swb & 31;
    const int h  = swb >> 5;
    const int q0 = qt * 64;

    const size_t qoff = (size_t)h * D_DIM;
    const size_t koff = E_DIM + (size_t)h * D_DIM;
    const size_t voff = 2 * E_DIM + (size_t)h * D_DIM;

    const int r  = t >> 2;          // 0..63
    const int s  = (t & 3) * 16;    // 0,16,32,48
    const int sw = (r & 7) << 3;
    const int kv = (t & 15) * 4;    // V-transpose source row group
    const int d0 = (t >> 4) * 4;    // V-transpose dest row group

    // --- stage Q (XOR-swizzled rows) ---
    {
        const unsigned short* gq = &proj[(size_t)(q0 + r) * LDP + qoff + s];
        const uint4 v0 = ((const uint4*)gq)[0];
        const uint4 v1 = ((const uint4*)gq)[1];
        *(uint4*)&lds[Q_OFF + r * 64 + (s ^ sw)]       = v0;
        *(uint4*)&lds[Q_OFF + r * 64 + ((s + 8) ^ sw)] = v1;
    }

    uint4 ka, kb;
    u16x4 vr[4];
    auto load_kv = [&](int t0) {
        const unsigned short* gk = &proj[(size_t)(t0 + r) * LDP + koff + s];
        ka = ((const uint4*)gk)[0];
        kb = ((const uint4*)gk)[1];
#pragma unroll
        for (int r2 = 0; r2 < 4; ++r2)
            vr[r2] = *(const u16x4*)&proj[(size_t)(t0 + kv + r2) * LDP + voff + d0];
    };
    auto store_kv = [&]() {
        *(uint4*)&lds[K_OFF + r * 64 + (s ^ sw)]       = ka;
        *(uint4*)&lds[K_OFF + r * 64 + ((s + 8) ^ sw)] = kb;
#pragma unroll
        for (int j = 0; j < 4; ++j) {
            u16x4 w; w[0] = vr[0][j]; w[1] = vr[1][j]; w[2] = vr[2][j]; w[3] = vr[3][j];
            const int d = d0 + j;
            *(u16x4*)&lds[V_OFF + d * 64 + (kv ^ ((d & 7) << 3))] = w;
        }
    };

    load_kv(0);
    store_kv();
    load_kv(64);
    __syncthreads();

    // hoist Q fragments (B-operand of swapped QK^T): lane -> q=wid*16+lc
    bf16x8 qB0, qB1;
    {
        const int rq = wid * 16 + lc;
        const int swq = (rq & 7) << 3;
        qB0 = *(const bf16x8*)&lds[Q_OFF + rq * 64 + ((g * 8) ^ swq)];
        qB1 = *(const bf16x8*)&lds[Q_OFF + rq * 64 + ((32 + g * 8) ^ swq)];
    }

    f32x4 oacc[4];
    const f32x4 zf = {0.f, 0.f, 0.f, 0.f};
#pragma unroll
    for (int i = 0; i < 4; ++i) oacc[i] = zf;
    float mrun = -1e30f, lrun = 0.f;

    const int pbase = (wid * 16 + lc) * 64;  // wave-private P row
    const int psw = (lc & 7) << 3;

    for (int tt = 0; tt < NT; ++tt) {
        // --- QK^T (swapped: A=K, B=Q) -> sacc[c][i] = S^T[kv=c*16+4g+i][q=lc]
        f32x4 sacc[4];
#pragma unroll
        for (int c = 0; c < 4; ++c) sacc[c] = zf;
#pragma unroll
        for (int c = 0; c < 4; ++c) {
            const int kr = c * 16 + lc;
            const int swk = (kr & 7) << 3;
            const bf16x8 kf = *(const bf16x8*)&lds[K_OFF + kr * 64 + ((g * 8) ^ swk)];
            sacc[c] = MFMA16(kf, qB0, sacc[c]);
        }
#pragma unroll
        for (int c = 0; c < 4; ++c) {
            const int kr = c * 16 + lc;
            const int swk = (kr & 7) << 3;
            const bf16x8 kf = *(const bf16x8*)&lds[K_OFF + kr * 64 + ((32 + g * 8) ^ swk)];
            sacc[c] = MFMA16(kf, qB1, sacc[c]);
        }

        // --- in-register softmax (lane owns its q-row; base-2 exp) ---
        const float mA = fmaxf(fmaxf(sacc[0][0], sacc[0][1]), fmaxf(sacc[0][2], sacc[0][3]));
        const float mB = fmaxf(fmaxf(sacc[1][0], sacc[1][1]), fmaxf(sacc[1][2], sacc[1][3]));
        const float mC = fmaxf(fmaxf(sacc[2][0], sacc[2][1]), fmaxf(sacc[2][2], sacc[2][3]));
        const float mD = fmaxf(fmaxf(sacc[3][0], sacc[3][1]), fmaxf(sacc[3][2], sacc[3][3]));
        float mx = fmaxf(fmaxf(mA, mB), fmaxf(mC, mD));
        mx = fmaxf(mx, __shfl_xor(mx, 16));
        mx = fmaxf(mx, __shfl_xor(mx, 32));
        const float mnew = fmaxf(mrun, mx);
        const float fs = exp2_fast(mrun - mnew);

        float p[4][4];
#pragma unroll
        for (int c = 0; c < 4; ++c)
#pragma unroll
            for (int i = 0; i < 4; ++i)
                p[c][i] = exp2_fast(sacc[c][i] - mnew);

        const float sA = (p[0][0] + p[0][1]) + (p[0][2] + p[0][3]);
        const float sB = (p[1][0] + p[1][1]) + (p[1][2] + p[1][3]);
        const float sC = (p[2][0] + p[2][1]) + (p[2][2] + p[2][3]);
        const float sD = (p[3][0] + p[3][1]) + (p[3][2] + p[3][3]);
        float ps = (sA + sB) + (sC + sD);
        ps += __shfl_xor(ps, 16);
        ps += __shfl_xor(ps, 32);
        lrun = lrun * fs + ps;
        mrun = mnew;

        // --- write P (4x b64, wave-private region) ---
#pragma unroll
        for (int c = 0; c < 4; ++c) {
            uint2 w;
            w.x = cvt_pk_bf16(p[c][0], p[c][1]);
            w.y = cvt_pk_bf16(p[c][2], p[c][3]);
            *(uint2*)&lds[P_OFF + pbase + ((c * 16 + 4 * g) ^ psw)] = w;
        }

        // --- rescale O (fs redistributed: oacc rows are q=4g+i) ---
#pragma unroll
        for (int i = 0; i < 4; ++i) {
            const float fsi = __shfl(fs, 4 * g + i, 16);
            oacc[0][i] *= fsi; oacc[1][i] *= fsi;
            oacc[2][i] *= fsi; oacc[3][i] *= fsi;
        }

        // --- P fragments (A-operand of PV) ---
        const bf16x8 pA0 = *(const bf16x8*)&lds[P_OFF + pbase + ((g * 8) ^ psw)];
        const bf16x8 pA1 = *(const bf16x8*)&lds[P_OFF + pbase + ((32 + g * 8) ^ psw)];

        // --- PV ---
#pragma unroll
        for (int dt = 0; dt < 4; ++dt) {
            const int vrow = dt * 16 + lc;
            const int swv = (vrow & 7) << 3;
            const bf16x8 vB = *(const bf16x8*)&lds[V_OFF + vrow * 64 + ((g * 8) ^ swv)];
            oacc[dt] = MFMA16(pA0, vB, oacc[dt]);
        }
#pragma unroll
        for (int dt = 0; dt < 4; ++dt) {
            const int vrow = dt * 16 + lc;
            const int swv = (vrow & 7) << 3;
            const bf16x8 vB = *(const bf16x8*)&lds[V_OFF + vrow * 64 + ((32 + g * 8) ^ swv)];
            oacc[dt] = MFMA16(pA1, vB, oacc[dt]);
        }

        __syncthreads();               // all waves done reading K/V
        if (tt < NT - 1) {
            store_kv();                // tile tt+1 -> LDS
            if (tt < NT - 2) load_kv((tt + 2) * 64);  // prefetch tt+2 -> regs
            __syncthreads();           // staging visible
        }
    }

    // --- epilogue: normalize, split f16 hi/lo for GEMM2 ---
    const float inv = 1.f / lrun;
#pragma unroll
    for (int i = 0; i < 4; ++i) {
        const float invi = __shfl(inv, 4 * g + i, 16);
        const int row = q0 + wid * 16 + 4 * g + i;
#pragma unroll
        for (int dt = 0; dt < 4; ++dt) {
            const float x = oacc[dt][i] * invi;
            const _Float16 xh = (_Float16)x;
            const _Float16 xl = (_Float16)(x - (float)xh);
            const size_t off = (size_t)row * E_DIM + h * D_DIM + dt * 16 + lc;
            Oh[off] = xh;
            Ol[off] = xl;
        }
    }
}

// ---------------------------------------------------------------------------
extern "C" void kernel_launch(void* const* d_in, const int* in_sizes, int n_in,
                              void* d_out, int out_size, void* d_ws, size_t ws_size,
                              hipStream_t stream)
{
    (void)in_sizes; (void)n_in; (void)out_size; (void)ws_size;

    const float* qkv   = (const float*)d_in[0];
    const float* w_in  = (const float*)d_in[1];
    const float* b_in  = (const float*)d_in[2];
    const float* w_out = (const float*)d_in[3];
    const float* b_out = (const float*)d_in[4];
    float* out = (float*)d_out;

    unsigned char* ws = (unsigned char*)d_ws;
    _Float16* Wt1 = (_Float16*)(ws);                          // 6.29 MB [3072][1024]
    _Float16* Wt2 = (_Float16*)(ws + 6291456);                // 2.10 MB [1024][1024]
    _Float16* Ah1 = (_Float16*)(ws + 8388608);                // 4.19 MB [2048][1024]
    _Float16* Al1 = (_Float16*)(ws + 12582912);               // 4.19 MB
    unsigned short* proj = (unsigned short*)(ws + 16777216);  // 12.58 MB bf16 [2048][3072]
    _Float16* Oh = Ah1;   // reuse: Ah1/Al1 dead after gemm1
    _Float16* Ol = Al1;

    // 1) prep: split A, transpose+convert weights
    split_a_kernel<<<2048, 256, 0, stream>>>(qkv, Ah1, Al1, S_LEN * E_DIM / 4);
    transpose_convert_kernel<<<dim3(48, 16), 256, 0, stream>>>(w_in, Wt1, E_DIM, 3 * E_DIM);
    transpose_convert_kernel<<<dim3(16, 16), 256, 0, stream>>>(w_out, Wt2, E_DIM, E_DIM);

    // 2) proj = qkv @ w_in + b_in (bf16 out, q-part pre-scaled)
    gemm_f16_kernel<1><<<384, 256, 0, stream>>>(
        Ah1, Al1, Wt1, b_in, (void*)proj, S_LEN, 3 * E_DIM, E_DIM, 24);

    // 3) flash attention -> Oh/Ol f16 hi/lo
    attn_mfma_kernel<<<512, 256, 0, stream>>>(proj, Oh, Ol);

    // 4) out = attn @ w_out + b_out (fp32 out)
    gemm_f16_kernel<0><<<128, 256, 0, stream>>>(
        Oh, Ol, Wt2, b_out, (void*)out, S_LEN, E_DIM, E_DIM, 8);
}

// Round 4
// 121.056 us; speedup vs baseline: 4.6003x; 1.2085x over previous
//
#include <hip/hip_runtime.h>
#include <math.h>

typedef short bf16x8 __attribute__((ext_vector_type(8)));
typedef _Float16 f16x8 __attribute__((ext_vector_type(8)));
typedef _Float16 f16x4 __attribute__((ext_vector_type(4)));
typedef float f32x4 __attribute__((ext_vector_type(4)));
typedef unsigned short u16x4 __attribute__((ext_vector_type(4)));
typedef unsigned short u16x8 __attribute__((ext_vector_type(8)));

#define S_LEN 2048
#define E_DIM 1024
#define H_NUM 16
#define D_DIM 64
#define LDP   (3 * E_DIM)
#define KVB   128
#define NT2   (S_LEN / KVB)
// softmax scale folded into Q at GEMM1 epilogue: 1/sqrt(64) * log2(e)
#define QSCALE 0.18033688011112042f

#define MFMA16(a, b, c)  __builtin_amdgcn_mfma_f32_16x16x32_bf16((a), (b), (c), 0, 0, 0)
#define MFMA16H(a, b, c) __builtin_amdgcn_mfma_f32_16x16x32_f16((a), (b), (c), 0, 0, 0)

__device__ __forceinline__ unsigned short f2bf(float f) {
    union { float f; unsigned int u; } v; v.f = f;
    unsigned int r = v.u + 0x7FFFu + ((v.u >> 16) & 1u);
    return (unsigned short)(r >> 16);
}
__device__ __forceinline__ float exp2_fast(float x) {
    float r; asm("v_exp_f32 %0, %1" : "=v"(r) : "v"(x)); return r;
}
__device__ __forceinline__ unsigned int cvt_pk_bf16(float lo, float hi) {
    unsigned int r;
    asm("v_cvt_pk_bf16_f32 %0, %1, %2" : "=v"(r) : "v"(lo), "v"(hi));
    return r;
}
// direct global -> LDS, 16B per lane. LDS dest = wave-uniform base + lane*16.
__device__ __forceinline__ void gl_lds16(const void* g, unsigned short* l) {
    __builtin_amdgcn_global_load_lds(
        (const __attribute__((address_space(1))) void*)g,
        (__attribute__((address_space(3))) void*)l, 16, 0, 0);
}

// ---------------------------------------------------------------------------
// Fused prep: [0,2048) split qkv fp32 -> f16 hi/lo; [2048,2816) transpose
// w_in -> f16 [N][K]; [2816,3072) transpose w_out -> f16 [N][K].
// ---------------------------------------------------------------------------
__global__ __launch_bounds__(256) void prep_kernel(
    const float* __restrict__ qkv, _Float16* __restrict__ Ah, _Float16* __restrict__ Al,
    const float* __restrict__ w_in, _Float16* __restrict__ Wt1,
    const float* __restrict__ w_out, _Float16* __restrict__ Wt2)
{
    __shared__ float tile[64][65];
    const int bid = blockIdx.x;
    const int t = threadIdx.x;

    if (bid < 2048) {           // split_a
        const int i = bid * 256 + t;
        const float4 v = ((const float4*)qkv)[i];
        f16x4 h, l;
        h[0] = (_Float16)v.x; l[0] = (_Float16)(v.x - (float)h[0]);
        h[1] = (_Float16)v.y; l[1] = (_Float16)(v.y - (float)h[1]);
        h[2] = (_Float16)v.z; l[2] = (_Float16)(v.z - (float)h[2]);
        h[3] = (_Float16)v.w; l[3] = (_Float16)(v.w - (float)h[3]);
        ((f16x4*)Ah)[i] = h;
        ((f16x4*)Al)[i] = l;
        return;
    }
    const float* B;
    _Float16* Bt;
    int bx, by, N;
    if (bid < 2816) { B = w_in;  Bt = Wt1; N = 3 * E_DIM; bx = (bid - 2048) % 48; by = (bid - 2048) / 48; }
    else            { B = w_out; Bt = Wt2; N = E_DIM;     bx = (bid - 2816) % 16; by = (bid - 2816) / 16; }
    const int K = E_DIM;
    const int k0 = by * 64, n0 = bx * 64;
    const int r4 = t >> 6, c = t & 63;
#pragma unroll
    for (int rep = 0; rep < 16; ++rep)
        tile[rep * 4 + r4][c] = B[(size_t)(k0 + rep * 4 + r4) * N + n0 + c];
    __syncthreads();
#pragma unroll
    for (int rep = 0; rep < 16; ++rep) {
        const int n = rep * 4 + r4;
        Bt[(size_t)(n0 + n) * K + k0 + c] = (_Float16)tile[c][n];
    }
}

// ---------------------------------------------------------------------------
// 2-pass f16 MFMA GEMM, global_load_lds staging + LDS double buffer.
// C = (Ah+Al)[M,K] @ Bt^T + bias, Bt [N][K] f16. BMxBN tile, BK=32, 4 waves.
// Staged rows per step: [Ah BM | Al BM | B BN], each row 32 f16 = 64B, linear.
// OUT_MODE 1: bf16 out, cols < E_DIM scaled by QSCALE. OUT_MODE 0: fp32 out.
// ---------------------------------------------------------------------------
template <int BM, int BN, int OUT_MODE>
__global__ __launch_bounds__(256) void gemm_f16_kernel(
    const _Float16* __restrict__ Ah, const _Float16* __restrict__ Al,
    const _Float16* __restrict__ Bt, const float* __restrict__ bias,
    void* __restrict__ Cout, int M, int N, int K, int nbx)
{
    constexpr int ROWS = 2 * BM + BN;
    constexpr int EPW  = ROWS / 16 / 4;   // gload issues per wave per step
    constexpr int MI = BM / 32, NI = BN / 32;
    __shared__ unsigned short lds[2 * ROWS * 32];

    const int nwg = gridDim.x;
    const int bid = blockIdx.x;
    const int qch = nwg >> 3;
    const int swz = (bid & 7) * qch + (bid >> 3);
    const int n0 = (swz % nbx) * BN;
    const int m0 = (swz / nbx) * BM;

    const int t = threadIdx.x;
    const int wid = t >> 6, lane = t & 63;
    const int wr = wid >> 1, wc = wid & 1;
    const int lc = lane & 15, g = lane >> 4;
    const int lrow = lane >> 2;          // row within a 16-row issue
    const int lcol = (lane & 3) * 8;     // f16 col offset

    f32x4 acc[MI][NI];
    const f32x4 zf = {0.f, 0.f, 0.f, 0.f};
#pragma unroll
    for (int mi = 0; mi < MI; ++mi)
#pragma unroll
        for (int ni = 0; ni < NI; ++ni) acc[mi][ni] = zf;

    auto stage = [&](int k0, int b) {
        unsigned short* base = &lds[b * ROWS * 32];
#pragma unroll
        for (int e = 0; e < EPW; ++e) {
            const int rb = (wid * EPW + e) * 16;
            const int r = rb + lrow;
            const _Float16* gp;
            if (rb < BM)          gp = &Ah[(size_t)(m0 + r) * K + k0 + lcol];
            else if (rb < 2 * BM) gp = &Al[(size_t)(m0 + r - BM) * K + k0 + lcol];
            else                  gp = &Bt[(size_t)(n0 + r - 2 * BM) * K + k0 + lcol];
            gl_lds16(gp, base + rb * 32);
        }
    };

    stage(0, 0);
    const int NK = K / 32;
    for (int ks = 0; ks < NK; ++ks) {
        __syncthreads();                         // drains vmcnt for buf[ks&1]
        if (ks + 1 < NK) stage((ks + 1) * 32, (ks + 1) & 1);  // fly during compute
        const unsigned short* cb = &lds[(ks & 1) * ROWS * 32];

        f16x8 bfr[NI];
#pragma unroll
        for (int ni = 0; ni < NI; ++ni)
            bfr[ni] = *(const f16x8*)&cb[(2 * BM + wc * (BN / 2) + ni * 16 + lc) * 32 + g * 8];
#pragma unroll
        for (int mi = 0; mi < MI; ++mi) {
            const int ar = wr * (BM / 2) + mi * 16 + lc;
            const f16x8 ah = *(const f16x8*)&cb[ar * 32 + g * 8];
            const f16x8 al = *(const f16x8*)&cb[(BM + ar) * 32 + g * 8];
#pragma unroll
            for (int ni = 0; ni < NI; ++ni)
                acc[mi][ni] = MFMA16H(ah, bfr[ni], acc[mi][ni]);
#pragma unroll
            for (int ni = 0; ni < NI; ++ni)
                acc[mi][ni] = MFMA16H(al, bfr[ni], acc[mi][ni]);
        }
    }

#pragma unroll
    for (int ni = 0; ni < NI; ++ni) {
        const int col = n0 + wc * (BN / 2) + ni * 16 + lc;
        const float bv = bias[col];
        float sc = 1.f;
        if (OUT_MODE == 1) sc = (col < E_DIM) ? QSCALE : 1.f;
#pragma unroll
        for (int mi = 0; mi < MI; ++mi) {
            const int rbase = m0 + wr * (BM / 2) + mi * 16 + g * 4;
#pragma unroll
            for (int i = 0; i < 4; ++i) {
                const float v = acc[mi][ni][i] + bv;
                if (OUT_MODE == 1)
                    ((unsigned short*)Cout)[(size_t)(rbase + i) * N + col] = f2bf(v * sc);
                else
                    ((float*)Cout)[(size_t)(rbase + i) * N + col] = v;
            }
        }
    }
}

// ---------------------------------------------------------------------------
// MFMA flash attention, swapped QK^T, KVBLK=128, K/V double-buffered in LDS,
// one barrier per iteration. proj bf16 [S][3E], Q pre-scaled by QSCALE.
// Block = 64 Q rows x head, 4 waves (16 q-rows each). P region overlays Q.
// ---------------------------------------------------------------------------
__global__ __launch_bounds__(256) void attn_mfma_kernel(
    const unsigned short* __restrict__ proj,
    _Float16* __restrict__ Oh, _Float16* __restrict__ Ol)
{
    // K: [2][128 kv][64 d] @0/8192 | Vt: [2][64 d][128 kv] @16384/24576 | QP @32768
    __shared__ unsigned short lds[36864];   // 72 KB
    const int KB0 = 0, VB0 = 16384, QP = 32768;

    const int t = threadIdx.x;
    const int wid = t >> 6, lane = t & 63;
    const int lc = lane & 15, g = lane >> 4;

    const int bid = blockIdx.x;
    const int swb = (bid & 7) * 64 + (bid >> 3);
    const int qt = swb & 31;
    const int h  = swb >> 5;
    const int q0 = qt * 64;

    const size_t qoff = (size_t)h * D_DIM;
    const size_t koff = E_DIM + (size_t)h * D_DIM;
    const size_t voff = 2 * E_DIM + (size_t)h * D_DIM;

    // staging coords
    const int kr_ = t >> 1;             // 0..127 K row
    const int ks_ = (t & 1) * 32;       // K col base
    const int vk4 = (t & 31) * 4;       // V kv base
    const int vd0 = (t >> 5) * 8;       // V d base

    uint4 kreg[4];
    u16x8 vreg[4];
    auto load_kv = [&](int t0) {
        const unsigned short* gk = &proj[(size_t)(t0 + kr_) * LDP + koff + ks_];
        kreg[0] = ((const uint4*)gk)[0];
        kreg[1] = ((const uint4*)gk)[1];
        kreg[2] = ((const uint4*)gk)[2];
        kreg[3] = ((const uint4*)gk)[3];
#pragma unroll
        for (int r2 = 0; r2 < 4; ++r2)
            vreg[r2] = *(const u16x8*)&proj[(size_t)(t0 + vk4 + r2) * LDP + voff + vd0];
    };
    auto store_kv = [&](int b) {
        const int kb = KB0 + b * 8192;
#pragma unroll
        for (int j = 0; j < 4; ++j)
            *(uint4*)&lds[kb + kr_ * 64 + ((ks_ + j * 8) ^ ((kr_ & 7) << 3))] = kreg[j];
        const int vb = VB0 + b * 8192;
#pragma unroll
        for (int j = 0; j < 8; ++j) {
            const int d = vd0 + j;
            u16x4 w;
            w[0] = vreg[0][j]; w[1] = vreg[1][j]; w[2] = vreg[2][j]; w[3] = vreg[3][j];
            *(u16x4*)&lds[vb + d * 128 + (vk4 ^ ((d & 7) << 3))] = w;
        }
    };

    // --- stage Q ---
    {
        const int r = t >> 2, sQ = (t & 3) * 16;
        const unsigned short* gq = &proj[(size_t)(q0 + r) * LDP + qoff + sQ];
        const uint4 v0 = ((const uint4*)gq)[0];
        const uint4 v1 = ((const uint4*)gq)[1];
        const int sw = (r & 7) << 3;
        *(uint4*)&lds[QP + r * 64 + (sQ ^ sw)]       = v0;
        *(uint4*)&lds[QP + r * 64 + ((sQ + 8) ^ sw)] = v1;
    }
    load_kv(0);
    store_kv(0);
    __syncthreads();

    // hoist Q fragments (wave reads only its own 16 rows; P overlay is safe)
    bf16x8 qB0, qB1;
    {
        const int rq = wid * 16 + lc;
        const int swq = (rq & 7) << 3;
        qB0 = *(const bf16x8*)&lds[QP + rq * 64 + ((g * 8) ^ swq)];
        qB1 = *(const bf16x8*)&lds[QP + rq * 64 + ((32 + g * 8) ^ swq)];
    }

    f32x4 oacc[4];
    const f32x4 zf = {0.f, 0.f, 0.f, 0.f};
#pragma unroll
    for (int i = 0; i < 4; ++i) oacc[i] = zf;
    float mrun = -1e30f, lrun = 0.f;

    const int pb = (wid * 16 + lc) * 64;   // wave-private P row (overlay on Q)
    const int psw = (lc & 7) << 3;

    for (int tt = 0; tt < NT2; ++tt) {
        if (tt + 1 < NT2) load_kv((tt + 1) * KVB);   // issue early (T14)
        const int kb = KB0 + (tt & 1) * 8192;
        const int vb = VB0 + (tt & 1) * 8192;

        // --- QK^T: sacc[c][i] = S[kv=c*16+4g+i][q=lc-owned row] ---
        f32x4 sacc[8];
#pragma unroll
        for (int c = 0; c < 8; ++c) sacc[c] = zf;
#pragma unroll
        for (int c = 0; c < 8; ++c) {
            const int krow = c * 16 + lc;
            const int swk = (krow & 7) << 3;
            const bf16x8 kf = *(const bf16x8*)&lds[kb + krow * 64 + ((g * 8) ^ swk)];
            sacc[c] = MFMA16(kf, qB0, sacc[c]);
        }
#pragma unroll
        for (int c = 0; c < 8; ++c) {
            const int krow = c * 16 + lc;
            const int swk = (krow & 7) << 3;
            const bf16x8 kf = *(const bf16x8*)&lds[kb + krow * 64 + ((32 + g * 8) ^ swk)];
            sacc[c] = MFMA16(kf, qB1, sacc[c]);
        }

        // --- in-register softmax over 32 values ---
        float cm[8];
#pragma unroll
        for (int c = 0; c < 8; ++c)
            cm[c] = fmaxf(fmaxf(sacc[c][0], sacc[c][1]), fmaxf(sacc[c][2], sacc[c][3]));
        float mx = fmaxf(fmaxf(fmaxf(cm[0], cm[1]), fmaxf(cm[2], cm[3])),
                         fmaxf(fmaxf(cm[4], cm[5]), fmaxf(cm[6], cm[7])));
        mx = fmaxf(mx, __shfl_xor(mx, 16));
        mx = fmaxf(mx, __shfl_xor(mx, 32));
        const float mnew = fmaxf(mrun, mx);
        const float fs = exp2_fast(mrun - mnew);
#pragma unroll
        for (int c = 0; c < 8; ++c)
#pragma unroll
            for (int i = 0; i < 4; ++i)
                sacc[c][i] = exp2_fast(sacc[c][i] - mnew);
        float cs[8];
#pragma unroll
        for (int c = 0; c < 8; ++c)
            cs[c] = (sacc[c][0] + sacc[c][1]) + (sacc[c][2] + sacc[c][3]);
        float ps = ((cs[0] + cs[1]) + (cs[2] + cs[3])) + ((cs[4] + cs[5]) + (cs[6] + cs[7]));
        ps += __shfl_xor(ps, 16);
        ps += __shfl_xor(ps, 32);
        lrun = lrun * fs + ps;
        mrun = mnew;

        // --- rescale O (fs redistributed to C-layout rows 4g+i) ---
#pragma unroll
        for (int i = 0; i < 4; ++i) {
            const float fsi = __shfl(fs, 4 * g + i, 16);
            oacc[0][i] *= fsi; oacc[1][i] *= fsi;
            oacc[2][i] *= fsi; oacc[3][i] *= fsi;
        }

        // --- PV in two kv-halves (P region reused; wave-private) ---
#pragma unroll
        for (int hf = 0; hf < 2; ++hf) {
#pragma unroll
            for (int c = 0; c < 4; ++c) {
                uint2 w;
                w.x = cvt_pk_bf16(sacc[hf * 4 + c][0], sacc[hf * 4 + c][1]);
                w.y = cvt_pk_bf16(sacc[hf * 4 + c][2], sacc[hf * 4 + c][3]);
                *(uint2*)&lds[QP + pb + ((c * 16 + 4 * g) ^ psw)] = w;
            }
            const bf16x8 pA0 = *(const bf16x8*)&lds[QP + pb + ((g * 8) ^ psw)];
            const bf16x8 pA1 = *(const bf16x8*)&lds[QP + pb + ((32 + g * 8) ^ psw)];
#pragma unroll
            for (int dt = 0; dt < 4; ++dt) {
                const int d = dt * 16 + lc;
                const int swv = (lc & 7) << 3;
                const bf16x8 v0 = *(const bf16x8*)&lds[vb + d * 128 + ((hf * 64 + g * 8) ^ swv)];
                const bf16x8 v1 = *(const bf16x8*)&lds[vb + d * 128 + ((hf * 64 + 32 + g * 8) ^ swv)];
                oacc[dt] = MFMA16(pA0, v0, oacc[dt]);
                oacc[dt] = MFMA16(pA1, v1, oacc[dt]);
            }
        }

        if (tt + 1 < NT2) store_kv((tt + 1) & 1);   // write other buffer
        __syncthreads();                            // one barrier per iter
    }

    // --- epilogue: normalize, split f16 hi/lo for GEMM2 ---
    const float inv = 1.f / lrun;
#pragma unroll
    for (int i = 0; i < 4; ++i) {
        const float invi = __shfl(inv, 4 * g + i, 16);
        const int row = q0 + wid * 16 + 4 * g + i;
#pragma unroll
        for (int dt = 0; dt < 4; ++dt) {
            const float x = oacc[dt][i] * invi;
            const _Float16 xh = (_Float16)x;
            const _Float16 xl = (_Float16)(x - (float)xh);
            const size_t off = (size_t)row * E_DIM + h * D_DIM + dt * 16 + lc;
            Oh[off] = xh;
            Ol[off] = xl;
        }
    }
}

// ---------------------------------------------------------------------------
extern "C" void kernel_launch(void* const* d_in, const int* in_sizes, int n_in,
                              void* d_out, int out_size, void* d_ws, size_t ws_size,
                              hipStream_t stream)
{
    (void)in_sizes; (void)n_in; (void)out_size; (void)ws_size;

    const float* qkv   = (const float*)d_in[0];
    const float* w_in  = (const float*)d_in[1];
    const float* b_in  = (const float*)d_in[2];
    const float* w_out = (const float*)d_in[3];
    const float* b_out = (const float*)d_in[4];
    float* out = (float*)d_out;

    unsigned char* ws = (unsigned char*)d_ws;
    _Float16* Wt1 = (_Float16*)(ws);                          // 6.29 MB [3072][1024]
    _Float16* Wt2 = (_Float16*)(ws + 6291456);                // 2.10 MB [1024][1024]
    _Float16* Ah1 = (_Float16*)(ws + 8388608);                // 4.19 MB [2048][1024]
    _Float16* Al1 = (_Float16*)(ws + 12582912);               // 4.19 MB
    unsigned short* proj = (unsigned short*)(ws + 16777216);  // 12.58 MB bf16 [2048][3072]
    _Float16* Oh = Ah1;   // reuse: Ah1/Al1 dead after gemm1
    _Float16* Ol = Al1;

    // 1) fused prep: split A + transpose both weights
    prep_kernel<<<3072, 256, 0, stream>>>(qkv, Ah1, Al1, w_in, Wt1, w_out, Wt2);

    // 2) proj = qkv @ w_in + b_in (bf16 out, q-part pre-scaled)
    gemm_f16_kernel<128, 128, 1><<<384, 256, 0, stream>>>(
        Ah1, Al1, Wt1, b_in, (void*)proj, S_LEN, 3 * E_DIM, E_DIM, 24);

    // 3) flash attention -> Oh/Ol f16 hi/lo
    attn_mfma_kernel<<<512, 256, 0, stream>>>(proj, Oh, Ol);

    // 4) out = attn @ w_out + b_out (fp32 out)
    gemm_f16_kernel<64, 64, 0><<<512, 256, 0, stream>>>(
        Oh, Ol, Wt2, b_out, (void*)out, S_LEN, E_DIM, E_DIM, 16);
}

// Round 5
// 103.287 us; speedup vs baseline: 5.3917x; 1.1720x over previous
//
#include <hip/hip_runtime.h>
#include <math.h>

typedef short bf16x8 __attribute__((ext_vector_type(8)));
typedef _Float16 f16x8 __attribute__((ext_vector_type(8)));
typedef _Float16 f16x4 __attribute__((ext_vector_type(4)));
typedef float f32x4 __attribute__((ext_vector_type(4)));
typedef unsigned short u16x4 __attribute__((ext_vector_type(4)));

#define S_LEN 2048
#define E_DIM 1024
#define H_NUM 16
#define D_DIM 64
#define LDP   (3 * E_DIM)
// softmax scale folded into Q at GEMM1 epilogue: 1/sqrt(64) * log2(e)
#define QSCALE 0.18033688011112042f

#define MFMA16(a, b, c)  __builtin_amdgcn_mfma_f32_16x16x32_bf16((a), (b), (c), 0, 0, 0)
#define MFMA16H(a, b, c) __builtin_amdgcn_mfma_f32_16x16x32_f16((a), (b), (c), 0, 0, 0)

__device__ __forceinline__ unsigned short f2bf(float f) {
    union { float f; unsigned int u; } v; v.f = f;
    unsigned int r = v.u + 0x7FFFu + ((v.u >> 16) & 1u);
    return (unsigned short)(r >> 16);
}
__device__ __forceinline__ float exp2_fast(float x) {
    float r; asm("v_exp_f32 %0, %1" : "=v"(r) : "v"(x)); return r;
}
__device__ __forceinline__ unsigned int cvt_pk_bf16(float lo, float hi) {
    unsigned int r;
    asm("v_cvt_pk_bf16_f32 %0, %1, %2" : "=v"(r) : "v"(lo), "v"(hi));
    return r;
}
// direct global -> LDS, 16B per lane. LDS dest = wave-uniform base + lane*16.
__device__ __forceinline__ void gl_lds16(const void* g, unsigned short* l) {
    __builtin_amdgcn_global_load_lds(
        (const __attribute__((address_space(1))) void*)g,
        (__attribute__((address_space(3))) void*)l, 16, 0, 0);
}

// ---------------------------------------------------------------------------
// Fused prep: [0,2048) split qkv fp32 -> f16 hi/lo; [2048,2816) transpose
// w_in -> f16 [N][K]; [2816,3072) transpose w_out -> f16 [N][K].
// ---------------------------------------------------------------------------
__global__ __launch_bounds__(256) void prep_kernel(
    const float* __restrict__ qkv, _Float16* __restrict__ Ah, _Float16* __restrict__ Al,
    const float* __restrict__ w_in, _Float16* __restrict__ Wt1,
    const float* __restrict__ w_out, _Float16* __restrict__ Wt2)
{
    __shared__ float tile[64][65];
    const int bid = blockIdx.x;
    const int t = threadIdx.x;

    if (bid < 2048) {           // split_a
        const int i = bid * 256 + t;
        const float4 v = ((const float4*)qkv)[i];
        f16x4 h, l;
        h[0] = (_Float16)v.x; l[0] = (_Float16)(v.x - (float)h[0]);
        h[1] = (_Float16)v.y; l[1] = (_Float16)(v.y - (float)h[1]);
        h[2] = (_Float16)v.z; l[2] = (_Float16)(v.z - (float)h[2]);
        h[3] = (_Float16)v.w; l[3] = (_Float16)(v.w - (float)h[3]);
        ((f16x4*)Ah)[i] = h;
        ((f16x4*)Al)[i] = l;
        return;
    }
    const float* B;
    _Float16* Bt;
    int bx, by, N;
    if (bid < 2816) { B = w_in;  Bt = Wt1; N = 3 * E_DIM; bx = (bid - 2048) % 48; by = (bid - 2048) / 48; }
    else            { B = w_out; Bt = Wt2; N = E_DIM;     bx = (bid - 2816) % 16; by = (bid - 2816) / 16; }
    const int K = E_DIM;
    const int k0 = by * 64, n0 = bx * 64;
    const int r4 = t >> 6, c = t & 63;
#pragma unroll
    for (int rep = 0; rep < 16; ++rep)
        tile[rep * 4 + r4][c] = B[(size_t)(k0 + rep * 4 + r4) * N + n0 + c];
    __syncthreads();
#pragma unroll
    for (int rep = 0; rep < 16; ++rep) {
        const int n = rep * 4 + r4;
        Bt[(size_t)(n0 + n) * K + k0 + c] = (_Float16)tile[c][n];
    }
}

// ---------------------------------------------------------------------------
// 2-pass f16 MFMA GEMM, global_load_lds staging + LDS double buffer.
// C = (Ah+Al)[M,K] @ Bt^T + bias, Bt [N][K] f16. BMxBN tile, BK=32, 4 waves.
// ---------------------------------------------------------------------------
template <int BM, int BN, int OUT_MODE>
__global__ __launch_bounds__(256) void gemm_f16_kernel(
    const _Float16* __restrict__ Ah, const _Float16* __restrict__ Al,
    const _Float16* __restrict__ Bt, const float* __restrict__ bias,
    void* __restrict__ Cout, int M, int N, int K, int nbx)
{
    constexpr int ROWS = 2 * BM + BN;
    constexpr int EPW  = ROWS / 16 / 4;
    constexpr int MI = BM / 32, NI = BN / 32;
    __shared__ unsigned short lds[2 * ROWS * 32];

    const int nwg = gridDim.x;
    const int bid = blockIdx.x;
    const int qch = nwg >> 3;
    const int swz = (bid & 7) * qch + (bid >> 3);
    const int n0 = (swz % nbx) * BN;
    const int m0 = (swz / nbx) * BM;

    const int t = threadIdx.x;
    const int wid = t >> 6, lane = t & 63;
    const int wr = wid >> 1, wc = wid & 1;
    const int lc = lane & 15, g = lane >> 4;
    const int lrow = lane >> 2;
    const int lcol = (lane & 3) * 8;

    f32x4 acc[MI][NI];
    const f32x4 zf = {0.f, 0.f, 0.f, 0.f};
#pragma unroll
    for (int mi = 0; mi < MI; ++mi)
#pragma unroll
        for (int ni = 0; ni < NI; ++ni) acc[mi][ni] = zf;

    auto stage = [&](int k0, int b) {
        unsigned short* base = &lds[b * ROWS * 32];
#pragma unroll
        for (int e = 0; e < EPW; ++e) {
            const int rb = (wid * EPW + e) * 16;
            const int r = rb + lrow;
            const _Float16* gp;
            if (rb < BM)          gp = &Ah[(size_t)(m0 + r) * K + k0 + lcol];
            else if (rb < 2 * BM) gp = &Al[(size_t)(m0 + r - BM) * K + k0 + lcol];
            else                  gp = &Bt[(size_t)(n0 + r - 2 * BM) * K + k0 + lcol];
            gl_lds16(gp, base + rb * 32);
        }
    };

    stage(0, 0);
    const int NK = K / 32;
    for (int ks = 0; ks < NK; ++ks) {
        __syncthreads();
        if (ks + 1 < NK) stage((ks + 1) * 32, (ks + 1) & 1);
        const unsigned short* cb = &lds[(ks & 1) * ROWS * 32];

        f16x8 bfr[NI];
#pragma unroll
        for (int ni = 0; ni < NI; ++ni)
            bfr[ni] = *(const f16x8*)&cb[(2 * BM + wc * (BN / 2) + ni * 16 + lc) * 32 + g * 8];
#pragma unroll
        for (int mi = 0; mi < MI; ++mi) {
            const int ar = wr * (BM / 2) + mi * 16 + lc;
            const f16x8 ah = *(const f16x8*)&cb[ar * 32 + g * 8];
            const f16x8 al = *(const f16x8*)&cb[(BM + ar) * 32 + g * 8];
#pragma unroll
            for (int ni = 0; ni < NI; ++ni)
                acc[mi][ni] = MFMA16H(ah, bfr[ni], acc[mi][ni]);
#pragma unroll
            for (int ni = 0; ni < NI; ++ni)
                acc[mi][ni] = MFMA16H(al, bfr[ni], acc[mi][ni]);
        }
    }

#pragma unroll
    for (int ni = 0; ni < NI; ++ni) {
        const int col = n0 + wc * (BN / 2) + ni * 16 + lc;
        const float bv = bias[col];
        float sc = 1.f;
        if (OUT_MODE == 1) sc = (col < E_DIM) ? QSCALE : 1.f;
#pragma unroll
        for (int mi = 0; mi < MI; ++mi) {
            const int rbase = m0 + wr * (BM / 2) + mi * 16 + g * 4;
#pragma unroll
            for (int i = 0; i < 4; ++i) {
                const float v = acc[mi][ni][i] + bv;
                if (OUT_MODE == 1)
                    ((unsigned short*)Cout)[(size_t)(rbase + i) * N + col] = f2bf(v * sc);
                else
                    ((float*)Cout)[(size_t)(rbase + i) * N + col] = v;
            }
        }
    }
}

// ---------------------------------------------------------------------------
// MFMA flash attention, swapped QK^T, split-KV. Block = 64 Q rows x head,
// 8 waves (512 thr): waves 0-3 process kv[0,1024), waves 4-7 kv[1024,2048),
// each wave owns 16 q-rows over its half. KVB=64, single K/V buffer per half
// + depth-2 register prefetch. Flash-merge of the two halves via LDS.
// ---------------------------------------------------------------------------
__global__ __launch_bounds__(512, 4) void attn_mfma_kernel(
    const unsigned short* __restrict__ proj,
    _Float16* __restrict__ Oh, _Float16* __restrict__ Ol)
{
    // K: [2 halves][64][64] @0 | Vt: [2][64 d][64 kv] @8192 | Q @16384 | P @20480
    __shared__ unsigned short lds[28672];   // 56 KB
    float* ldsf = (float*)lds;              // merge scratch overlays K/V (dead)
    const int K_BASE = 0, V_BASE = 8192, Q_OFF = 16384, P_OFF = 20480;

    const int t = threadIdx.x;
    const int w = t >> 6, lane = t & 63;
    const int lc = lane & 15, g = lane >> 4;
    const int qg = w & 3;        // q-row group (16 rows)
    const int half = w >> 2;     // kv half; staging group (t>>8) == half
    const int ts = t & 255;

    const int bid = blockIdx.x;
    const int swb = (bid & 7) * 64 + (bid >> 3);
    const int qt = swb & 31;
    const int h  = swb >> 5;
    const int q0 = qt * 64;

    const size_t qoff = (size_t)h * D_DIM;
    const size_t koff = E_DIM + (size_t)h * D_DIM;
    const size_t voff = 2 * E_DIM + (size_t)h * D_DIM;

    const int KO = K_BASE + half * 4096;
    const int VO = V_BASE + half * 4096;
    const int kvbase = half * (S_LEN / 2);

    // staging coords (within 256-thread group)
    const int r  = ts >> 2;           // 0..63
    const int s  = (ts & 3) * 16;     // 0,16,32,48
    const int sw = (r & 7) << 3;
    const int kv = (ts & 15) * 4;     // V-transpose src rows
    const int d0 = (ts >> 4) * 4;     // V-transpose dst rows

    uint4 ka, kb;
    u16x4 vr[4];
    auto load_kv = [&](int tile) {
        const int t0 = kvbase + tile * 64;
        const unsigned short* gk = &proj[(size_t)(t0 + r) * LDP + koff + s];
        ka = ((const uint4*)gk)[0];
        kb = ((const uint4*)gk)[1];
#pragma unroll
        for (int r2 = 0; r2 < 4; ++r2)
            vr[r2] = *(const u16x4*)&proj[(size_t)(t0 + kv + r2) * LDP + voff + d0];
    };
    auto store_kv = [&]() {
        *(uint4*)&lds[KO + r * 64 + (s ^ sw)]       = ka;
        *(uint4*)&lds[KO + r * 64 + ((s + 8) ^ sw)] = kb;
#pragma unroll
        for (int j = 0; j < 4; ++j) {
            u16x4 w4; w4[0] = vr[0][j]; w4[1] = vr[1][j]; w4[2] = vr[2][j]; w4[3] = vr[3][j];
            const int d = d0 + j;
            *(u16x4*)&lds[VO + d * 64 + (kv ^ ((d & 7) << 3))] = w4;
        }
    };

    // --- stage Q (group 0 only) ---
    if (half == 0) {
        const unsigned short* gq = &proj[(size_t)(q0 + r) * LDP + qoff + s];
        const uint4 v0 = ((const uint4*)gq)[0];
        const uint4 v1 = ((const uint4*)gq)[1];
        *(uint4*)&lds[Q_OFF + r * 64 + (s ^ sw)]       = v0;
        *(uint4*)&lds[Q_OFF + r * 64 + ((s + 8) ^ sw)] = v1;
    }
    load_kv(0);
    store_kv();
    load_kv(1);
    __syncthreads();

    // hoist Q fragments: lane owns q-row qg*16+lc
    bf16x8 qB0, qB1;
    {
        const int rq = qg * 16 + lc;
        const int swq = (rq & 7) << 3;
        qB0 = *(const bf16x8*)&lds[Q_OFF + rq * 64 + ((g * 8) ^ swq)];
        qB1 = *(const bf16x8*)&lds[Q_OFF + rq * 64 + ((32 + g * 8) ^ swq)];
    }

    f32x4 oacc[4];
    const f32x4 zf = {0.f, 0.f, 0.f, 0.f};
#pragma unroll
    for (int i = 0; i < 4; ++i) oacc[i] = zf;
    float mrun = -1e30f, lrun = 0.f;

    const int pb = P_OFF + (w * 16 + lc) * 64;   // wave-private P row
    const int psw = (lc & 7) << 3;

    const int NTH = (S_LEN / 2) / 64;   // 16 tiles per half
    for (int tt = 0; tt < NTH; ++tt) {
        // --- QK^T (swapped: A=K, B=Q): sacc[c][i] = S[kv=c*16+4g+i][q-row lc]
        f32x4 sacc[4];
#pragma unroll
        for (int c = 0; c < 4; ++c) sacc[c] = zf;
#pragma unroll
        for (int c = 0; c < 4; ++c) {
            const int kr = c * 16 + lc;
            const int swk = (kr & 7) << 3;
            const bf16x8 kf = *(const bf16x8*)&lds[KO + kr * 64 + ((g * 8) ^ swk)];
            sacc[c] = MFMA16(kf, qB0, sacc[c]);
        }
#pragma unroll
        for (int c = 0; c < 4; ++c) {
            const int kr = c * 16 + lc;
            const int swk = (kr & 7) << 3;
            const bf16x8 kf = *(const bf16x8*)&lds[KO + kr * 64 + ((32 + g * 8) ^ swk)];
            sacc[c] = MFMA16(kf, qB1, sacc[c]);
        }

        // --- in-register softmax (lane owns its q-row; base-2 domain) ---
        const float mA = fmaxf(fmaxf(sacc[0][0], sacc[0][1]), fmaxf(sacc[0][2], sacc[0][3]));
        const float mB = fmaxf(fmaxf(sacc[1][0], sacc[1][1]), fmaxf(sacc[1][2], sacc[1][3]));
        const float mC = fmaxf(fmaxf(sacc[2][0], sacc[2][1]), fmaxf(sacc[2][2], sacc[2][3]));
        const float mD = fmaxf(fmaxf(sacc[3][0], sacc[3][1]), fmaxf(sacc[3][2], sacc[3][3]));
        float mx = fmaxf(fmaxf(mA, mB), fmaxf(mC, mD));
        mx = fmaxf(mx, __shfl_xor(mx, 16));
        mx = fmaxf(mx, __shfl_xor(mx, 32));
        const float mnew = fmaxf(mrun, mx);
        const float fs = exp2_fast(mrun - mnew);

        float p[4][4];
#pragma unroll
        for (int c = 0; c < 4; ++c)
#pragma unroll
            for (int i = 0; i < 4; ++i)
                p[c][i] = exp2_fast(sacc[c][i] - mnew);

        const float sA = (p[0][0] + p[0][1]) + (p[0][2] + p[0][3]);
        const float sB = (p[1][0] + p[1][1]) + (p[1][2] + p[1][3]);
        const float sC = (p[2][0] + p[2][1]) + (p[2][2] + p[2][3]);
        const float sD = (p[3][0] + p[3][1]) + (p[3][2] + p[3][3]);
        float ps = (sA + sB) + (sC + sD);
        ps += __shfl_xor(ps, 16);
        ps += __shfl_xor(ps, 32);
        lrun = lrun * fs + ps;
        mrun = mnew;

        // --- write P (wave-private) ---
#pragma unroll
        for (int c = 0; c < 4; ++c) {
            uint2 w2;
            w2.x = cvt_pk_bf16(p[c][0], p[c][1]);
            w2.y = cvt_pk_bf16(p[c][2], p[c][3]);
            *(uint2*)&lds[pb + ((c * 16 + 4 * g) ^ psw)] = w2;
        }

        // --- rescale O (fs redistributed to C-layout rows 4g+i) ---
#pragma unroll
        for (int i = 0; i < 4; ++i) {
            const float fsi = __shfl(fs, 4 * g + i, 16);
            oacc[0][i] *= fsi; oacc[1][i] *= fsi;
            oacc[2][i] *= fsi; oacc[3][i] *= fsi;
        }

        // --- PV ---
        const bf16x8 pA0 = *(const bf16x8*)&lds[pb + ((g * 8) ^ psw)];
        const bf16x8 pA1 = *(const bf16x8*)&lds[pb + ((32 + g * 8) ^ psw)];
#pragma unroll
        for (int dt = 0; dt < 4; ++dt) {
            const int vrow = dt * 16 + lc;
            const int swv = (vrow & 7) << 3;
            const bf16x8 vB = *(const bf16x8*)&lds[VO + vrow * 64 + ((g * 8) ^ swv)];
            oacc[dt] = MFMA16(pA0, vB, oacc[dt]);
        }
#pragma unroll
        for (int dt = 0; dt < 4; ++dt) {
            const int vrow = dt * 16 + lc;
            const int swv = (vrow & 7) << 3;
            const bf16x8 vB = *(const bf16x8*)&lds[VO + vrow * 64 + ((32 + g * 8) ^ swv)];
            oacc[dt] = MFMA16(pA1, vB, oacc[dt]);
        }

        __syncthreads();                 // all waves done reading K/V
        if (tt + 1 < NTH) {
            store_kv();                  // tile tt+1 -> LDS
            if (tt + 2 < NTH) load_kv(tt + 2);
            __syncthreads();
        }
    }

    // --- flash-merge of the two halves (scratch overlays dead K/V) ---
    __syncthreads();
    if (half == 1) {
#pragma unroll
        for (int dt = 0; dt < 4; ++dt)
#pragma unroll
            for (int i = 0; i < 4; ++i)
                ldsf[qg * 1024 + (dt * 4 + i) * 64 + lane] = oacc[dt][i];
        ldsf[4096 + qg * 128 + lane] = mrun;
        ldsf[4096 + qg * 128 + 64 + lane] = lrun;
    }
    __syncthreads();
    if (half == 0) {
        const float m2 = ldsf[4096 + qg * 128 + lane];
        const float l2 = ldsf[4096 + qg * 128 + 64 + lane];
        const float mf = fmaxf(mrun, m2);
        const float f1 = exp2_fast(mrun - mf);
        const float f2 = exp2_fast(m2 - mf);
        const float inv = 1.f / (lrun * f1 + l2 * f2);
#pragma unroll
        for (int i = 0; i < 4; ++i) {
            const float f1i = __shfl(f1, 4 * g + i, 16);
            const float f2i = __shfl(f2, 4 * g + i, 16);
            const float invi = __shfl(inv, 4 * g + i, 16);
            const int row = q0 + qg * 16 + 4 * g + i;
#pragma unroll
            for (int dt = 0; dt < 4; ++dt) {
                const float o2 = ldsf[qg * 1024 + (dt * 4 + i) * 64 + lane];
                const float x = (oacc[dt][i] * f1i + o2 * f2i) * invi;
                const _Float16 xh = (_Float16)x;
                const _Float16 xl = (_Float16)(x - (float)xh);
                const size_t off = (size_t)row * E_DIM + h * D_DIM + dt * 16 + lc;
                Oh[off] = xh;
                Ol[off] = xl;
            }
        }
    }
}

// ---------------------------------------------------------------------------
extern "C" void kernel_launch(void* const* d_in, const int* in_sizes, int n_in,
                              void* d_out, int out_size, void* d_ws, size_t ws_size,
                              hipStream_t stream)
{
    (void)in_sizes; (void)n_in; (void)out_size; (void)ws_size;

    const float* qkv   = (const float*)d_in[0];
    const float* w_in  = (const float*)d_in[1];
    const float* b_in  = (const float*)d_in[2];
    const float* w_out = (const float*)d_in[3];
    const float* b_out = (const float*)d_in[4];
    float* out = (float*)d_out;

    unsigned char* ws = (unsigned char*)d_ws;
    _Float16* Wt1 = (_Float16*)(ws);                          // 6.29 MB [3072][1024]
    _Float16* Wt2 = (_Float16*)(ws + 6291456);                // 2.10 MB [1024][1024]
    _Float16* Ah1 = (_Float16*)(ws + 8388608);                // 4.19 MB [2048][1024]
    _Float16* Al1 = (_Float16*)(ws + 12582912);               // 4.19 MB
    unsigned short* proj = (unsigned short*)(ws + 16777216);  // 12.58 MB bf16 [2048][3072]
    _Float16* Oh = Ah1;   // reuse: Ah1/Al1 dead after gemm1
    _Float16* Ol = Al1;

    // 1) fused prep: split A + transpose both weights
    prep_kernel<<<3072, 256, 0, stream>>>(qkv, Ah1, Al1, w_in, Wt1, w_out, Wt2);

    // 2) proj = qkv @ w_in + b_in (bf16 out, q-part pre-scaled)
    gemm_f16_kernel<128, 128, 1><<<384, 256, 0, stream>>>(
        Ah1, Al1, Wt1, b_in, (void*)proj, S_LEN, 3 * E_DIM, E_DIM, 24);

    // 3) flash attention (split-KV, 8 waves) -> Oh/Ol f16 hi/lo
    attn_mfma_kernel<<<512, 512, 0, stream>>>(proj, Oh, Ol);

    // 4) out = attn @ w_out + b_out (fp32 out)
    gemm_f16_kernel<64, 64, 0><<<512, 256, 0, stream>>>(
        Oh, Ol, Wt2, b_out, (void*)out, S_LEN, E_DIM, E_DIM, 16);
}

// Round 6
// 91.041 us; speedup vs baseline: 6.1169x; 1.1345x over previous
//
#include <hip/hip_runtime.h>
#include <math.h>

typedef short bf16x8 __attribute__((ext_vector_type(8)));
typedef _Float16 f16x8 __attribute__((ext_vector_type(8)));
typedef _Float16 f16x4 __attribute__((ext_vector_type(4)));
typedef float f32x4 __attribute__((ext_vector_type(4)));
typedef unsigned short u16x4 __attribute__((ext_vector_type(4)));

#define S_LEN 2048
#define E_DIM 1024
#define H_NUM 16
#define D_DIM 64
#define LDP   (3 * E_DIM)
// softmax scale folded into Q at GEMM1 epilogue: 1/sqrt(64) * log2(e)
#define QSCALE 0.18033688011112042f

#define MFMA16(a, b, c)  __builtin_amdgcn_mfma_f32_16x16x32_bf16((a), (b), (c), 0, 0, 0)
#define MFMA16H(a, b, c) __builtin_amdgcn_mfma_f32_16x16x32_f16((a), (b), (c), 0, 0, 0)

__device__ __forceinline__ unsigned short f2bf(float f) {
    union { float f; unsigned int u; } v; v.f = f;
    unsigned int r = v.u + 0x7FFFu + ((v.u >> 16) & 1u);
    return (unsigned short)(r >> 16);
}
__device__ __forceinline__ float exp2_fast(float x) {
    float r; asm("v_exp_f32 %0, %1" : "=v"(r) : "v"(x)); return r;
}
__device__ __forceinline__ unsigned int cvt_pk_bf16(float lo, float hi) {
    unsigned int r;
    asm("v_cvt_pk_bf16_f32 %0, %1, %2" : "=v"(r) : "v"(lo), "v"(hi));
    return r;
}
// direct global -> LDS, 16B per lane. LDS dest = wave-uniform base + lane*16.
__device__ __forceinline__ void gl_lds16(const void* g, unsigned short* l) {
    __builtin_amdgcn_global_load_lds(
        (const __attribute__((address_space(1))) void*)g,
        (__attribute__((address_space(3))) void*)l, 16, 0, 0);
}

// ---------------------------------------------------------------------------
// Fused prep: [0,2048) convert qkv fp32 -> f16; [2048,2816) transpose w_in;
// [2816,3072) transpose w_out. (GEMM1 is 1-pass f16: proj is stored bf16, so
// A-lo adds nothing below the bf16 storage floor.)
// ---------------------------------------------------------------------------
__global__ __launch_bounds__(256) void prep_kernel(
    const float* __restrict__ qkv, _Float16* __restrict__ Ah,
    const float* __restrict__ w_in, _Float16* __restrict__ Wt1,
    const float* __restrict__ w_out, _Float16* __restrict__ Wt2)
{
    __shared__ float tile[64][65];
    const int bid = blockIdx.x;
    const int t = threadIdx.x;

    if (bid < 2048) {
        const int i = bid * 256 + t;
        const float4 v = ((const float4*)qkv)[i];
        f16x4 hh;
        hh[0] = (_Float16)v.x; hh[1] = (_Float16)v.y;
        hh[2] = (_Float16)v.z; hh[3] = (_Float16)v.w;
        ((f16x4*)Ah)[i] = hh;
        return;
    }
    const float* B;
    _Float16* Bt;
    int bx, by, N;
    if (bid < 2816) { B = w_in;  Bt = Wt1; N = 3 * E_DIM; bx = (bid - 2048) % 48; by = (bid - 2048) / 48; }
    else            { B = w_out; Bt = Wt2; N = E_DIM;     bx = (bid - 2816) % 16; by = (bid - 2816) / 16; }
    const int K = E_DIM;
    const int k0 = by * 64, n0 = bx * 64;
    const int r4 = t >> 6, c = t & 63;
#pragma unroll
    for (int rep = 0; rep < 16; ++rep)
        tile[rep * 4 + r4][c] = B[(size_t)(k0 + rep * 4 + r4) * N + n0 + c];
    __syncthreads();
#pragma unroll
    for (int rep = 0; rep < 16; ++rep) {
        const int n = rep * 4 + r4;
        Bt[(size_t)(n0 + n) * K + k0 + c] = (_Float16)tile[c][n];
    }
}

// ---------------------------------------------------------------------------
// f16 MFMA GEMM, global_load_lds staging + LDS double buffer.
// TWO_PASS=1: C = (Ah+Al) @ Bt^T + bias;  TWO_PASS=0: C = Ah @ Bt^T + bias.
// Bt is [N][K] f16. BMxBN tile, BK=32, 4 waves (2x2).
// ---------------------------------------------------------------------------
template <int BM, int BN, int OUT_MODE, int TWO_PASS>
__global__ __launch_bounds__(256) void gemm_f16_kernel(
    const _Float16* __restrict__ Ah, const _Float16* __restrict__ Al,
    const _Float16* __restrict__ Bt, const float* __restrict__ bias,
    void* __restrict__ Cout, int M, int N, int K, int nbx)
{
    constexpr int AROWS = TWO_PASS ? 2 * BM : BM;
    constexpr int ROWS = AROWS + BN;
    constexpr int EPW  = ROWS / 64;       // gload issues per wave per step
    constexpr int MI = BM / 32, NI = BN / 32;
    __shared__ unsigned short lds[2 * ROWS * 32];

    const int nwg = gridDim.x;
    const int bid = blockIdx.x;
    const int qch = nwg >> 3;
    const int swz = (bid & 7) * qch + (bid >> 3);
    const int n0 = (swz % nbx) * BN;
    const int m0 = (swz / nbx) * BM;

    const int t = threadIdx.x;
    const int wid = t >> 6, lane = t & 63;
    const int wr = wid >> 1, wc = wid & 1;
    const int lc = lane & 15, g = lane >> 4;
    const int lrow = lane >> 2;
    const int lcol = (lane & 3) * 8;

    f32x4 acc[MI][NI];
    const f32x4 zf = {0.f, 0.f, 0.f, 0.f};
#pragma unroll
    for (int mi = 0; mi < MI; ++mi)
#pragma unroll
        for (int ni = 0; ni < NI; ++ni) acc[mi][ni] = zf;

    auto stage = [&](int k0, int b) {
        unsigned short* base = &lds[b * ROWS * 32];
#pragma unroll
        for (int e = 0; e < EPW; ++e) {
            const int rb = (wid * EPW + e) * 16;
            const int rr = rb + lrow;
            const _Float16* gp;
            if (rb < BM)                            gp = &Ah[(size_t)(m0 + rr) * K + k0 + lcol];
            else if (TWO_PASS && rb < 2 * BM)       gp = &Al[(size_t)(m0 + rr - BM) * K + k0 + lcol];
            else                                    gp = &Bt[(size_t)(n0 + rr - AROWS) * K + k0 + lcol];
            gl_lds16(gp, base + rb * 32);
        }
    };

    stage(0, 0);
    const int NK = K / 32;
    for (int ks = 0; ks < NK; ++ks) {
        __syncthreads();
        if (ks + 1 < NK) stage((ks + 1) * 32, (ks + 1) & 1);
        const unsigned short* cb = &lds[(ks & 1) * ROWS * 32];

        f16x8 bfr[NI];
#pragma unroll
        for (int ni = 0; ni < NI; ++ni)
            bfr[ni] = *(const f16x8*)&cb[(AROWS + wc * (BN / 2) + ni * 16 + lc) * 32 + g * 8];
#pragma unroll
        for (int mi = 0; mi < MI; ++mi) {
            const int ar = wr * (BM / 2) + mi * 16 + lc;
            const f16x8 ah = *(const f16x8*)&cb[ar * 32 + g * 8];
#pragma unroll
            for (int ni = 0; ni < NI; ++ni)
                acc[mi][ni] = MFMA16H(ah, bfr[ni], acc[mi][ni]);
            if (TWO_PASS) {
                const f16x8 al = *(const f16x8*)&cb[(BM + ar) * 32 + g * 8];
#pragma unroll
                for (int ni = 0; ni < NI; ++ni)
                    acc[mi][ni] = MFMA16H(al, bfr[ni], acc[mi][ni]);
            }
        }
    }

#pragma unroll
    for (int ni = 0; ni < NI; ++ni) {
        const int col = n0 + wc * (BN / 2) + ni * 16 + lc;
        const float bv = bias[col];
        float sc = 1.f;
        if (OUT_MODE == 1) sc = (col < E_DIM) ? QSCALE : 1.f;
#pragma unroll
        for (int mi = 0; mi < MI; ++mi) {
            const int rbase = m0 + wr * (BM / 2) + mi * 16 + g * 4;
#pragma unroll
            for (int i = 0; i < 4; ++i) {
                const float v = acc[mi][ni][i] + bv;
                if (OUT_MODE == 1)
                    ((unsigned short*)Cout)[(size_t)(rbase + i) * N + col] = f2bf(v * sc);
                else
                    ((float*)Cout)[(size_t)(rbase + i) * N + col] = v;
            }
        }
    }
}

// ---------------------------------------------------------------------------
// MFMA flash attention, swapped QK^T, split-KV, defer-max online softmax.
// Block = 64 Q rows x head, 8 waves (512 thr): waves 0-3 kv[0,1024),
// waves 4-7 kv[1024,2048). KVB=64, K/V double-buffered -> 1 barrier/iter.
// Common path has ZERO cross-lane ops: per-lane max + __any threshold check
// (T13), per-lane partial l-sum reduced once after the loop.
// ---------------------------------------------------------------------------
__global__ __launch_bounds__(512, 4) void attn_mfma_kernel(
    const unsigned short* __restrict__ proj,
    _Float16* __restrict__ Oh, _Float16* __restrict__ Ol)
{
    // K: [2 half][2 buf][64][64] @0 | Vt: same @16384 | Q (P overlay) @32768
    __shared__ unsigned short lds[36864];   // 72 KB -> 2 blocks/CU
    float* ldsf = (float*)lds;              // merge scratch overlays dead K
    const int Q_OFF = 32768;

    const int t = threadIdx.x;
    const int w = t >> 6, lane = t & 63;
    const int lc = lane & 15, g = lane >> 4;
    const int qg = w & 3;        // q-row group (16 rows)
    const int half = w >> 2;     // kv half
    const int ts = t & 255;

    const int bid = blockIdx.x;
    const int swb = (bid & 7) * 64 + (bid >> 3);
    const int qt = swb & 31;
    const int h  = swb >> 5;
    const int q0 = qt * 64;

    const size_t qoff = (size_t)h * D_DIM;
    const size_t koff = E_DIM + (size_t)h * D_DIM;
    const size_t voff = 2 * E_DIM + (size_t)h * D_DIM;

    const int KH = half * 8192;          // K base for this half
    const int VH = 16384 + half * 8192;  // V base for this half
    const int kvbase = half * (S_LEN / 2);

    // staging coords (within 256-thread half-group)
    const int r  = ts >> 2;           // 0..63
    const int s  = (ts & 3) * 16;     // 0,16,32,48
    const int sw = (r & 7) << 3;
    const int kv = (ts & 15) * 4;     // V-transpose src rows
    const int d0 = (ts >> 4) * 4;     // V-transpose dst rows

    uint4 ka, kb;
    u16x4 vr[4];
    auto load_kv = [&](int tile) {
        const int t0 = kvbase + tile * 64;
        const unsigned short* gk = &proj[(size_t)(t0 + r) * LDP + koff + s];
        ka = ((const uint4*)gk)[0];
        kb = ((const uint4*)gk)[1];
#pragma unroll
        for (int r2 = 0; r2 < 4; ++r2)
            vr[r2] = *(const u16x4*)&proj[(size_t)(t0 + kv + r2) * LDP + voff + d0];
    };
    auto store_kv = [&](int b) {
        const int KO = KH + b * 4096, VO = VH + b * 4096;
        *(uint4*)&lds[KO + r * 64 + (s ^ sw)]       = ka;
        *(uint4*)&lds[KO + r * 64 + ((s + 8) ^ sw)] = kb;
#pragma unroll
        for (int j = 0; j < 4; ++j) {
            u16x4 w4; w4[0] = vr[0][j]; w4[1] = vr[1][j]; w4[2] = vr[2][j]; w4[3] = vr[3][j];
            const int d = d0 + j;
            *(u16x4*)&lds[VO + d * 64 + (kv ^ ((d & 7) << 3))] = w4;
        }
    };

    // --- prologue: stage Q (group 0), K/V tile 0; prefetch tile 1 ---
    if (half == 0) {
        const unsigned short* gq = &proj[(size_t)(q0 + r) * LDP + qoff + s];
        const uint4 v0 = ((const uint4*)gq)[0];
        const uint4 v1 = ((const uint4*)gq)[1];
        *(uint4*)&lds[Q_OFF + r * 64 + (s ^ sw)]       = v0;
        *(uint4*)&lds[Q_OFF + r * 64 + ((s + 8) ^ sw)] = v1;
    }
    load_kv(0);
    store_kv(0);
    load_kv(1);
    __syncthreads();

    // hoist Q fragments: lane owns q-row qg*16+lc
    bf16x8 qB0, qB1;
    {
        const int rq = qg * 16 + lc;
        const int swq = (rq & 7) << 3;
        qB0 = *(const bf16x8*)&lds[Q_OFF + rq * 64 + ((g * 8) ^ swq)];
        qB1 = *(const bf16x8*)&lds[Q_OFF + rq * 64 + ((32 + g * 8) ^ swq)];
    }
    __syncthreads();   // all waves hoisted Q before P overlays the region

    f32x4 oacc[4];
    const f32x4 zf = {0.f, 0.f, 0.f, 0.f};
#pragma unroll
    for (int i = 0; i < 4; ++i) oacc[i] = zf;
    float mrun = -1e30f;   // row-uniform high-water mark (T13 defer-max)
    float lsum = 0.f;      // per-lane partial sum (reduced after loop)

    // per-wave P chunk: 16 rows x 32 kv-cols, overlaid on Q region
    const int pb = Q_OFF + w * 512 + lc * 32;
    const int psw = (lc & 3) << 3;

    const int NTH = (S_LEN / 2) / 64;   // 16 tiles per half
    for (int tt = 0; tt < NTH; ++tt) {
        const int KO = KH + (tt & 1) * 4096;
        const int VO = VH + (tt & 1) * 4096;

        // --- QK^T (swapped: A=K, B=Q): sacc[c][i] = S[kv=c*16+4g+i][q=lc] ---
        f32x4 sacc[4];
#pragma unroll
        for (int c = 0; c < 4; ++c) sacc[c] = zf;
        __builtin_amdgcn_s_setprio(1);
#pragma unroll
        for (int c = 0; c < 4; ++c) {
            const int kr = c * 16 + lc;
            const int swk = (kr & 7) << 3;
            const bf16x8 kf = *(const bf16x8*)&lds[KO + kr * 64 + ((g * 8) ^ swk)];
            sacc[c] = MFMA16(kf, qB0, sacc[c]);
        }
#pragma unroll
        for (int c = 0; c < 4; ++c) {
            const int kr = c * 16 + lc;
            const int swk = (kr & 7) << 3;
            const bf16x8 kf = *(const bf16x8*)&lds[KO + kr * 64 + ((32 + g * 8) ^ swk)];
            sacc[c] = MFMA16(kf, qB1, sacc[c]);
        }
        __builtin_amdgcn_s_setprio(0);

        // --- defer-max check (no cross-lane data exchange in common path) ---
        float lmax = fmaxf(fmaxf(sacc[0][0], sacc[0][1]), fmaxf(sacc[0][2], sacc[0][3]));
        lmax = fmaxf(lmax, fmaxf(fmaxf(sacc[1][0], sacc[1][1]), fmaxf(sacc[1][2], sacc[1][3])));
        lmax = fmaxf(lmax, fmaxf(fmaxf(sacc[2][0], sacc[2][1]), fmaxf(sacc[2][2], sacc[2][3])));
        lmax = fmaxf(lmax, fmaxf(fmaxf(sacc[3][0], sacc[3][1]), fmaxf(sacc[3][2], sacc[3][3])));
        if (__any(lmax > mrun + 8.0f)) {   // rare after the first tiles
            float mx = lmax;
            mx = fmaxf(mx, __shfl_xor(mx, 16));
            mx = fmaxf(mx, __shfl_xor(mx, 32));
            const float mnew = fmaxf(mrun, mx);
            const float fs = exp2_fast(mrun - mnew);
            lsum *= fs;
            mrun = mnew;
#pragma unroll
            for (int i = 0; i < 4; ++i) {
                const float fsi = __shfl(fs, 4 * g + i, 16);
                oacc[0][i] *= fsi; oacc[1][i] *= fsi;
                oacc[2][i] *= fsi; oacc[3][i] *= fsi;
            }
        }

        // --- exp (base-2, stale max: P <= 2^8) + per-lane partial sum ---
#pragma unroll
        for (int c = 0; c < 4; ++c)
#pragma unroll
            for (int i = 0; i < 4; ++i)
                sacc[c][i] = exp2_fast(sacc[c][i] - mrun);
        lsum += ((sacc[0][0] + sacc[0][1]) + (sacc[0][2] + sacc[0][3]))
              + ((sacc[1][0] + sacc[1][1]) + (sacc[1][2] + sacc[1][3]))
              + ((sacc[2][0] + sacc[2][1]) + (sacc[2][2] + sacc[2][3]))
              + ((sacc[3][0] + sacc[3][1]) + (sacc[3][2] + sacc[3][3]));

        // --- PV in two kv-chunks (P chunk wave-private, overlays Q) ---
#pragma unroll
        for (int hf = 0; hf < 2; ++hf) {
#pragma unroll
            for (int c2 = 0; c2 < 2; ++c2) {
                const int c = hf * 2 + c2;
                uint2 w2;
                w2.x = cvt_pk_bf16(sacc[c][0], sacc[c][1]);
                w2.y = cvt_pk_bf16(sacc[c][2], sacc[c][3]);
                *(uint2*)&lds[pb + ((c2 * 16 + 4 * g) ^ psw)] = w2;
            }
            const bf16x8 pA = *(const bf16x8*)&lds[pb + ((g * 8) ^ psw)];
            __builtin_amdgcn_s_setprio(1);
#pragma unroll
            for (int dt = 0; dt < 4; ++dt) {
                const int vrow = dt * 16 + lc;
                const int swv = (vrow & 7) << 3;
                const bf16x8 vB = *(const bf16x8*)&lds[VO + vrow * 64 + ((hf * 32 + g * 8) ^ swv)];
                oacc[dt] = MFMA16(pA, vB, oacc[dt]);
            }
            __builtin_amdgcn_s_setprio(0);
        }

        // --- stage tile tt+1 (regs -> LDS other buf), prefetch tt+2 ---
        if (tt + 1 < NTH) {
            store_kv((tt + 1) & 1);
            if (tt + 2 < NTH) load_kv(tt + 2);
        }
        __syncthreads();   // single barrier per iteration
    }

    // --- final cross-lane l reduction (once) ---
    float ps = lsum;
    ps += __shfl_xor(ps, 16);
    ps += __shfl_xor(ps, 32);

    // --- flash-merge of the two halves (scratch overlays dead K region) ---
    if (half == 1) {
#pragma unroll
        for (int dt = 0; dt < 4; ++dt)
#pragma unroll
            for (int i = 0; i < 4; ++i)
                ldsf[qg * 1024 + (dt * 4 + i) * 64 + lane] = oacc[dt][i];
        ldsf[4096 + qg * 128 + lane] = mrun;
        ldsf[4096 + qg * 128 + 64 + lane] = ps;
    }
    __syncthreads();
    if (half == 0) {
        const float m2 = ldsf[4096 + qg * 128 + lane];
        const float l2 = ldsf[4096 + qg * 128 + 64 + lane];
        const float mf = fmaxf(mrun, m2);
        const float f1 = exp2_fast(mrun - mf);
        const float f2 = exp2_fast(m2 - mf);
        const float inv = 1.f / (ps * f1 + l2 * f2);
#pragma unroll
        for (int i = 0; i < 4; ++i) {
            const float f1i = __shfl(f1, 4 * g + i, 16);
            const float f2i = __shfl(f2, 4 * g + i, 16);
            const float invi = __shfl(inv, 4 * g + i, 16);
            const int row = q0 + qg * 16 + 4 * g + i;
#pragma unroll
            for (int dt = 0; dt < 4; ++dt) {
                const float o2 = ldsf[qg * 1024 + (dt * 4 + i) * 64 + lane];
                const float x = (oacc[dt][i] * f1i + o2 * f2i) * invi;
                const _Float16 xh = (_Float16)x;
                const _Float16 xl = (_Float16)(x - (float)xh);
                const size_t off = (size_t)row * E_DIM + h * D_DIM + dt * 16 + lc;
                Oh[off] = xh;
                Ol[off] = xl;
            }
        }
    }
}

// ---------------------------------------------------------------------------
extern "C" void kernel_launch(void* const* d_in, const int* in_sizes, int n_in,
                              void* d_out, int out_size, void* d_ws, size_t ws_size,
                              hipStream_t stream)
{
    (void)in_sizes; (void)n_in; (void)out_size; (void)ws_size;

    const float* qkv   = (const float*)d_in[0];
    const float* w_in  = (const float*)d_in[1];
    const float* b_in  = (const float*)d_in[2];
    const float* w_out = (const float*)d_in[3];
    const float* b_out = (const float*)d_in[4];
    float* out = (float*)d_out;

    unsigned char* ws = (unsigned char*)d_ws;
    _Float16* Wt1 = (_Float16*)(ws);                          // 6.29 MB [3072][1024]
    _Float16* Wt2 = (_Float16*)(ws + 6291456);                // 2.10 MB [1024][1024]
    _Float16* Ah1 = (_Float16*)(ws + 8388608);                // 4.19 MB [2048][1024]
    _Float16* Al1 = (_Float16*)(ws + 12582912);               // 4.19 MB (attn Ol)
    unsigned short* proj = (unsigned short*)(ws + 16777216);  // 12.58 MB bf16 [2048][3072]
    _Float16* Oh = Ah1;   // reuse: Ah1 dead after gemm1
    _Float16* Ol = Al1;

    // 1) fused prep: convert A to f16 + transpose both weights
    prep_kernel<<<3072, 256, 0, stream>>>(qkv, Ah1, w_in, Wt1, w_out, Wt2);

    // 2) proj = qkv @ w_in + b_in (1-pass f16, bf16 out, q-part pre-scaled)
    gemm_f16_kernel<128, 128, 1, 0><<<384, 256, 0, stream>>>(
        Ah1, Ah1, Wt1, b_in, (void*)proj, S_LEN, 3 * E_DIM, E_DIM, 24);

    // 3) flash attention (split-KV, defer-max) -> Oh/Ol f16 hi/lo
    attn_mfma_kernel<<<512, 512, 0, stream>>>(proj, Oh, Ol);

    // 4) out = attn @ w_out + b_out (2-pass f16, fp32 out)
    gemm_f16_kernel<64, 64, 0, 1><<<512, 256, 0, stream>>>(
        Oh, Ol, Wt2, b_out, (void*)out, S_LEN, E_DIM, E_DIM, 16);
}